// Round 15
// baseline (110.509 us; speedup 1.0000x reference)
//
#include <hip/hip_runtime.h>
#include <hip/hip_bf16.h>
#include <math.h>

// Problem dims
#define TOK   8192
#define F_DIM 64
#define U_DIM 128
#define N3    384

// Chebyshev expansion
#define MCH   64
#define KCH   (F_DIM * MCH)      // 4096
#define RCH   6.0f

// GEMM tiling: KSPL=4, BM=64, BK=64 (1 feature/step), 512 thr (8 waves)
#define BM    64
#define BK    64
#define KSPL  4
#define KRANGE (KCH / KSPL)      // 1024
#define NST   (KRANGE / BK)      // 16
#define NF    16
#define ASTR  72

typedef _Float16 h16x8 __attribute__((ext_vector_type(8)));
typedef __bf16   bf16x8 __attribute__((ext_vector_type(8)));
typedef float    f32x4 __attribute__((ext_vector_type(4)));

#define WG_SYNC() do {                                       \
    asm volatile("s_waitcnt lgkmcnt(0)" ::: "memory");       \
    __builtin_amdgcn_s_barrier();                            \
    __builtin_amdgcn_sched_barrier(0);                       \
} while (0)

__device__ __forceinline__ float bflo(unsigned u) { u <<= 16; return __builtin_bit_cast(float, u); }
__device__ __forceinline__ float bfhi(unsigned u) { u &= 0xffff0000u; return __builtin_bit_cast(float, u); }
__device__ __forceinline__ unsigned bfpack(float a, float b) {
    unsigned pa = (unsigned)__builtin_bit_cast(unsigned short, (__bf16)a);
    unsigned pb = (unsigned)__builtin_bit_cast(unsigned short, (__bf16)b);
    return pa | (pb << 16);
}

// ---------------------------------------------------------------------------
// Kernel 1 (R14-validated): blocks 0..191 = (mat=bx>>6, f=bx&63): Chebyshev
// fit in-LDS (exact erf-gelu) + C-build, packed f16 GEMM layout.
// Blocks 192..203: pack lin_w/sm_w into MFMA B-frag order.
// ---------------------------------------------------------------------------
__global__ __launch_bounds__(256) void vsn_prep15(
    const float* __restrict__ fw,
    const float* __restrict__ fb,
    const float* __restrict__ elu_w,
    const float* __restrict__ gate_w,
    const float* __restrict__ proj_w,
    const float* __restrict__ lin_w,
    const float* __restrict__ sm_w,
    _Float16* __restrict__ Cw,
    __bf16* __restrict__ linf,
    __bf16* __restrict__ smf)
{
    const int t = threadIdx.x;
    const int bx = blockIdx.x;
    if (bx >= 192) {
        const int xb = bx - 192;
        if (xb < 8) {
#pragma unroll
            for (int i = 0; i < 8; ++i) {
                int idx = xb * 2048 + i * 256 + t;
                int j = idx & 7, l = (idx >> 3) & 63, q = idx >> 9;
                int ks = q >> 3, nj = q & 7;
                int k = ks * 32 + (l >> 4) * 8 + j;
                int n = nj * 16 + (l & 15);
                linf[idx] = (__bf16)lin_w[k * U_DIM + n];
            }
        } else {
            int sb = xb - 8;
#pragma unroll
            for (int i = 0; i < 8; ++i) {
                int idx = sb * 2048 + i * 256 + t;
                int j = idx & 7, l = (idx >> 3) & 63, q = idx >> 9;
                int ks = q >> 2, nj = q & 3;
                int k = ks * 32 + (l >> 4) * 8 + j;
                int n = nj * 16 + (l & 15);
                smf[idx] = (__bf16)sm_w[k * F_DIM + n];
            }
        }
        return;
    }

    __shared__ float ctab[MCH][67];
    __shared__ float g_lds[128][67];
    __shared__ float c_lds[128 * MCH];
    __shared__ float w_lds[32 * 128];

    const int f = bx & 63, mat = bx >> 6;
    const float* W = (mat == 0) ? elu_w : (mat == 1 ? gate_w : proj_w);
    const int kg0 = f * 128;

#pragma unroll
    for (int r = 0; r < 16; ++r) {
        int idx = r * 256 + t;
        int m = idx >> 6, i = idx & 63;
        float ang = 3.14159265358979f * (float)m * ((float)i + 0.5f) * (1.0f / 64.0f);
        ctab[m][i] = cosf(ang) * (2.0f / 64.0f) * (m == 0 ? 0.5f : 1.0f);
    }
    __syncthreads();

#pragma unroll 4
    for (int r = 0; r < 32; ++r) {
        int idx = r * 256 + t;
        int k = idx >> 6, i = idx & 63;
        float xi = ctab[1][i] * (RCH * 32.0f);
        float z = fmaf(fw[kg0 + k], xi, fb[kg0 + k]);
        g_lds[k][i] = 0.5f * z * (1.0f + erff(z * 0.70710678f));
    }
    __syncthreads();

    {
        const int k = t & 127, mh = t >> 7;
#pragma unroll 4
        for (int mm = 0; mm < 32; ++mm) {
            int m = mh * 32 + mm;
            float a = 0.f;
#pragma unroll
            for (int i = 0; i < 64; ++i)
                a = fmaf(g_lds[k][i], ctab[m][i], a);
            c_lds[k * MCH + m] = a;
        }
    }
    __syncthreads();

    const int n0 = (t & 31) * 4;
    const int mq = t >> 5;
    float acc[8][4];
#pragma unroll
    for (int e = 0; e < 8; ++e)
#pragma unroll
        for (int q = 0; q < 4; ++q) acc[e][q] = 0.f;

    for (int jc = 0; jc < 4; ++jc) {
        __syncthreads();
        {
            const f32x4* src = (const f32x4*)&W[(size_t)(kg0 + jc * 32) * U_DIM];
            f32x4* dst = (f32x4*)w_lds;
#pragma unroll
            for (int r = 0; r < 4; ++r) dst[r * 256 + t] = src[r * 256 + t];
        }
        __syncthreads();

#pragma unroll 4
        for (int jj = 0; jj < 32; ++jj) {
            const int j = jc * 32 + jj;
            f32x4 wv  = *(const f32x4*)&w_lds[jj * 128 + n0];
            f32x4 cv0 = *(const f32x4*)&c_lds[j * MCH + mq * 8];
            f32x4 cv1 = *(const f32x4*)&c_lds[j * MCH + mq * 8 + 4];
#pragma unroll
            for (int e = 0; e < 4; ++e)
#pragma unroll
                for (int q = 0; q < 4; ++q) {
                    acc[e][q]     = fmaf(cv0[e], wv[q], acc[e][q]);
                    acc[e + 4][q] = fmaf(cv1[e], wv[q], acc[e + 4][q]);
                }
        }
    }

    const int kb = mq >> 2;
    const int ko = (mq & 3) * 8;
#pragma unroll
    for (int q = 0; q < 4; ++q) {
        const int ng = mat * U_DIM + n0 + q;
        h16x8 v;
#pragma unroll
        for (int e = 0; e < 8; ++e) v[e] = (_Float16)acc[e][q];
        *(h16x8*)&Cw[(((size_t)(f * 2 + kb) * N3) + ng) * 32 + ko] = v;
    }
}

// ---------------------------------------------------------------------------
// Kernel 2: Chebyshev GEMM — 512 thr (8 waves 2m x 4n), acc[2][6],
// __launch_bounds__(512,2) -> 4 waves/SIMD (vs R12's 2): doubled TLP,
// identical traffic (m-band waves re-read same B-frags via L1).
// grid (KSPL=4, 128) = 512 WGs = 2 WGs/CU. XCD id%8 in {s,s+4}.
// ---------------------------------------------------------------------------
__global__ __launch_bounds__(512, 2) void vsn_gemm15(
    const float* __restrict__ x,
    const _Float16* __restrict__ Cw,
    __bf16* __restrict__ Hp)
{
    __shared__ float     x_lds[BM][NF + 1];    // 4.4 KB
    __shared__ _Float16  a_lds[2][BM][ASTR];   // 18.4 KB

    const int t    = threadIdx.x;
    const int wave = t >> 6;
    const int lane = t & 63;
    const int s     = blockIdx.x;
    const int tok0  = blockIdx.y * BM;
    const int kbase = s * KRANGE;
    const int wm = wave >> 2;                  // 0..1 : 32-row band
    const int wn = wave & 3;                   // 0..3 : 96-col band
    const int nbase = wn * 96;
    const int lr  = lane & 15;
    const int lk8 = (lane >> 4) * 8;

    // stage x (64 tok x 16 feats), 2 elems/thread
#pragma unroll
    for (int i = 0; i < 2; ++i) {
        int idx = i * 512 + t;
        x_lds[idx >> 4][idx & 15] =
            x[(size_t)(tok0 + (idx >> 4)) * F_DIM + (kbase >> 6) + (idx & 15)];
    }

    f32x4 acc[2][6];
#pragma unroll
    for (int i = 0; i < 2; ++i)
#pragma unroll
        for (int j = 0; j < 6; ++j)
            acc[i][j] = (f32x4){0.f, 0.f, 0.f, 0.f};

    const int m_a = t >> 3;          // 0..63: token row
    const int q   = t & 7;           // m-strip: m0 = q*8

    // A-tile: T_m(x~), m in [q*8, q*8+8), feature = st  (R14-validated chain)
    auto cheb_write = [&](int st, int buf) {
        float xr = x_lds[m_a][st];
        float xt = fminf(fmaxf(xr * (1.0f / RCH), -1.0f), 1.0f);
        float x2 = xt + xt;
        float s1 = sqrtf(fmaxf(fmaf(-xt, xt, 1.0f), 0.0f));
        float T2 = fmaf(x2, xt, -1.0f),      S2 = x2 * s1;
        float T4 = fmaf(T2 + T2, T2, -1.0f), S4 = (T2 + T2) * S2;
        float T8 = fmaf(T4 + T4, T4, -1.0f), S8 = (T4 + T4) * S4;
        float T16 = fmaf(T8 + T8, T8, -1.0f),    S16 = (T8 + T8) * S8;
        float T24 = fmaf(T16, T8, -S16 * S8),    S24 = fmaf(S16, T8, T16 * S8);
        float T32 = fmaf(T16 + T16, T16, -1.0f), S32 = (T16 + T16) * S16;
        float T40 = fmaf(T32, T8, -S32 * S8),    S40 = fmaf(S32, T8, T32 * S8);
        float T48 = fmaf(T24 + T24, T24, -1.0f), S48 = (T24 + T24) * S24;
        float T56 = fmaf(T48, T8, -S48 * S8),    S56 = fmaf(S48, T8, T48 * S8);
        float Ta = (q == 0) ? 1.0f : (q == 1) ? T8 : (q == 2) ? T16 :
                   (q == 3) ? T24 : (q == 4) ? T32 : (q == 5) ? T40 :
                   (q == 6) ? T48 : T56;
        float Sa = (q == 0) ? 0.0f : (q == 1) ? S8 : (q == 2) ? S16 :
                   (q == 3) ? S24 : (q == 4) ? S32 : (q == 5) ? S40 :
                   (q == 6) ? S48 : S56;
        float v0 = Ta;
        float v1 = fmaf(xt, Ta, -Sa * s1);
        h16x8 o;
        o[0] = (_Float16)v0; o[1] = (_Float16)v1;
#pragma unroll
        for (int i = 2; i < 8; ++i) {
            float v = fmaf(x2, v1, -v0); v0 = v1; v1 = v;
            o[i] = (_Float16)v;
        }
        *(h16x8*)&a_lds[buf][m_a][q * 8] = o;
    };

    const _Float16* bb = Cw + (size_t)(kbase >> 5) * (N3 * 32)
                            + (nbase + lr) * 32 + lk8;
    auto loadB = [&](int st, int ksi, h16x8 (&dst)[6]) {
        const _Float16* p = bb + (size_t)(st * 2 + ksi) * (N3 * 32);
#pragma unroll
        for (int j = 0; j < 6; ++j)
            dst[j] = *(const h16x8*)(p + j * 512);
    };

#define MFMA_HALF(B, KSI, CUR) do {                                         \
        h16x8 af_[2];                                                       \
        _Pragma("unroll")                                                   \
        for (int i_ = 0; i_ < 2; ++i_)                                      \
            af_[i_] = *(const h16x8*)                                       \
                &a_lds[CUR][wm * 32 + i_ * 16 + lr][(KSI) * 32 + lk8];      \
        __builtin_amdgcn_s_setprio(1);                                      \
        _Pragma("unroll")                                                   \
        for (int i_ = 0; i_ < 2; ++i_)                                      \
            _Pragma("unroll")                                               \
            for (int j_ = 0; j_ < 6; ++j_)                                  \
                acc[i_][j_] = __builtin_amdgcn_mfma_f32_16x16x32_f16(       \
                    af_[i_], B[j_], acc[i_][j_], 0, 0, 0);                  \
        __builtin_amdgcn_s_setprio(0);                                      \
    } while (0)

    h16x8 bX[6], bY[6];

    WG_SYNC();                     // x staged
    cheb_write(0, 0);
    loadB(0, 0, bX);

    for (int st = 0; st < NST - 1; ++st) {
        const int cur = st & 1;
        WG_SYNC();                 // a_lds[cur] ready; buf cur^1 free
        loadB(st, 1, bY);
        cheb_write(st + 1, cur ^ 1);
        MFMA_HALF(bX, 0, cur);
        loadB(st + 1, 0, bX);
        MFMA_HALF(bY, 1, cur);
    }
    {
        const int cur = (NST - 1) & 1;
        WG_SYNC();
        loadB(NST - 1, 1, bY);
        MFMA_HALF(bX, 0, cur);
        MFMA_HALF(bY, 1, cur);
    }
#undef MFMA_HALF

    // write bf16 partials (C/D: col=lane&15, row=(lane>>4)*4+r)
    __bf16* Hs = Hp + (size_t)s * ((size_t)TOK * N3);
    const int r0 = (lane >> 4) * 4;
#pragma unroll
    for (int i = 0; i < 2; ++i)
#pragma unroll
        for (int j = 0; j < 6; ++j)
#pragma unroll
            for (int r = 0; r < 4; ++r)
                Hs[(size_t)(tok0 + wm * 32 + i * 16 + r0 + r) * N3
                   + nbase + j * 16 + lr] = (__bf16)acc[i][j][r];
}

// ---------------------------------------------------------------------------
// Kernel 3: MFMA epilogue (R13 lean variant, validated). 256 WGs x 128 thr.
// ---------------------------------------------------------------------------
__global__ __launch_bounds__(128) void vsn_epi15(
    const float* __restrict__ x,
    const __bf16* __restrict__ Hp,
    const __bf16* __restrict__ linf,
    const __bf16* __restrict__ smf,
    const float* __restrict__ elu_b,
    const float* __restrict__ lin_b,
    const float* __restrict__ gate_b,
    const float* __restrict__ ln_g,
    const float* __restrict__ ln_b,
    const float* __restrict__ sm_b,
    float* __restrict__ out)
{
    __shared__ __bf16   h1_lds[2][16][136];
    __shared__ unsigned g_lds[2][16][66];
    __shared__ float    p_lds[2][16][132];

    const int t = threadIdx.x, w = t >> 6, lane = t & 63;
    const int tokb = blockIdx.x * 32 + w * 16;

    const float2 eb = *(const float2*)&elu_b[2 * lane];
    const float2 gb = *(const float2*)&gate_b[2 * lane];
#pragma unroll 4
    for (int tk = 0; tk < 16; ++tk) {
        const unsigned short* base =
            (const unsigned short*)Hp + (size_t)(tokb + tk) * N3;
        float a0 = 0.f, a1 = 0.f, g0 = 0.f, g1 = 0.f, p0 = 0.f, p1 = 0.f;
#pragma unroll
        for (int s = 0; s < KSPL; ++s) {
            const unsigned short* bs = base + (size_t)s * TOK * N3;
            unsigned ua = *(const unsigned*)(bs + 2 * lane);
            unsigned ug = *(const unsigned*)(bs + 128 + 2 * lane);
            unsigned up = *(const unsigned*)(bs + 256 + 2 * lane);
            a0 += bflo(ua); a1 += bfhi(ua);
            g0 += bflo(ug); g1 += bfhi(ug);
            p0 += bflo(up); p1 += bfhi(up);
        }
        float e0 = a0 + eb.x, e1 = a1 + eb.y;
        float h10 = (e0 > 0.f) ? e0 : expm1f(e0);
        float h11 = (e1 > 0.f) ? e1 : expm1f(e1);
        *(unsigned*)((char*)&h1_lds[w][tk][0] + 4 * lane) = bfpack(h10, h11);
        float ga  = 1.f / (1.f + __expf(-(g0 + gb.x)));
        float gbv = 1.f / (1.f + __expf(-(g1 + gb.y)));
        g_lds[w][tk][lane] = bfpack(ga, gbv);
        p_lds[w][tk][2 * lane]     = p0;
        p_lds[w][tk][2 * lane + 1] = p1;
    }
    __syncthreads();

    const int c0 = lane & 15;
    const int rg = lane >> 4;

    f32x4 acc[8];
#pragma unroll
    for (int nj = 0; nj < 8; ++nj) acc[nj] = (f32x4){0.f, 0.f, 0.f, 0.f};
#pragma unroll
    for (int ks = 0; ks < 4; ++ks) {
        bf16x8 af = *(const bf16x8*)&h1_lds[w][c0][ks * 32 + rg * 8];
#pragma unroll
        for (int nj = 0; nj < 8; ++nj) {
            bf16x8 bf = *(const bf16x8*)&linf[((ks * 8 + nj) * 64 + lane) * 8];
            acc[nj] = __builtin_amdgcn_mfma_f32_16x16x32_bf16(af, bf, acc[nj], 0, 0, 0);
        }
    }

    float h[8][4];
#pragma unroll
    for (int nj = 0; nj < 8; ++nj) {
        float lb = lin_b[c0 + 16 * nj];
        int colh = (c0 + 16 * nj) >> 1;
        int odd  = c0 & 1;
#pragma unroll
        for (int r = 0; r < 4; ++r) {
            int tokr = rg * 4 + r;
            float h2 = acc[nj][r] + lb;
            unsigned gu = g_lds[w][tokr][colh];
            float g = odd ? bfhi(gu) : bflo(gu);
            float p = p_lds[w][tokr][c0 + 16 * nj];
            h[nj][r] = fmaf(g, h2, p);
        }
    }

    float mu[4], rstd[4];
#pragma unroll
    for (int r = 0; r < 4; ++r) {
        float s = 0.f;
#pragma unroll
        for (int nj = 0; nj < 8; ++nj) s += h[nj][r];
        s += __shfl_xor(s, 1); s += __shfl_xor(s, 2);
        s += __shfl_xor(s, 4); s += __shfl_xor(s, 8);
        mu[r] = s * (1.0f / 128.0f);
        float v = 0.f;
#pragma unroll
        for (int nj = 0; nj < 8; ++nj) {
            float d = h[nj][r] - mu[r];
            v = fmaf(d, d, v);
        }
        v += __shfl_xor(v, 1); v += __shfl_xor(v, 2);
        v += __shfl_xor(v, 4); v += __shfl_xor(v, 8);
        rstd[r] = rsqrtf(v * (1.0f / 128.0f) + 1e-3f);
    }

#pragma unroll
    for (int nj = 0; nj < 8; ++nj) {
        int col = c0 + 16 * nj;
        float lg = ln_g[col], lb = ln_b[col];
#pragma unroll
        for (int r = 0; r < 4; ++r) {
            float y = fmaf((h[nj][r] - mu[r]) * rstd[r], lg, lb);
            h1_lds[w][rg * 4 + r][col] = (__bf16)y;
        }
    }

    f32x4 acc2[4];
#pragma unroll
    for (int nj = 0; nj < 4; ++nj) acc2[nj] = (f32x4){0.f, 0.f, 0.f, 0.f};
#pragma unroll
    for (int ks = 0; ks < 4; ++ks) {
        bf16x8 af = *(const bf16x8*)&h1_lds[w][c0][ks * 32 + rg * 8];
#pragma unroll
        for (int nj = 0; nj < 4; ++nj) {
            bf16x8 bf = *(const bf16x8*)&smf[((ks * 4 + nj) * 64 + lane) * 8];
            acc2[nj] = __builtin_amdgcn_mfma_f32_16x16x32_bf16(af, bf, acc2[nj], 0, 0, 0);
        }
    }

    float lgt[4][4];
#pragma unroll
    for (int nj = 0; nj < 4; ++nj) {
        float sb = sm_b[c0 + 16 * nj];
#pragma unroll
        for (int r = 0; r < 4; ++r) lgt[nj][r] = acc2[nj][r] + sb;
    }
#pragma unroll
    for (int r = 0; r < 4; ++r) {
        float mx = fmaxf(fmaxf(lgt[0][r], lgt[1][r]), fmaxf(lgt[2][r], lgt[3][r]));
        mx = fmaxf(mx, __shfl_xor(mx, 1)); mx = fmaxf(mx, __shfl_xor(mx, 2));
        mx = fmaxf(mx, __shfl_xor(mx, 4)); mx = fmaxf(mx, __shfl_xor(mx, 8));
        float ex[4], se = 0.f;
#pragma unroll
        for (int nj = 0; nj < 4; ++nj) {
            ex[nj] = __expf(lgt[nj][r] - mx);
            se += ex[nj];
        }
        se += __shfl_xor(se, 1); se += __shfl_xor(se, 2);
        se += __shfl_xor(se, 4); se += __shfl_xor(se, 8);
        float inv = 1.0f / se;
        int tok = tokb + rg * 4 + r;
#pragma unroll
        for (int nj = 0; nj < 4; ++nj) {
            int f = c0 + 16 * nj;
            float wgt = ex[nj] * inv;
            float xv = x[(size_t)tok * F_DIM + f];
            out[(size_t)tok * F_DIM + f] = xv * wgt;
            out[(size_t)TOK * F_DIM + (size_t)tok * F_DIM + f] = wgt;
        }
    }
}

// ---------------------------------------------------------------------------
extern "C" void kernel_launch(void* const* d_in, const int* in_sizes, int n_in,
                              void* d_out, int out_size, void* d_ws, size_t ws_size,
                              hipStream_t stream)
{
    const float* x      = (const float*)d_in[0];
    const float* fw     = (const float*)d_in[1];
    const float* fb     = (const float*)d_in[2];
    const float* elu_w  = (const float*)d_in[3];
    const float* elu_b  = (const float*)d_in[4];
    const float* lin_w  = (const float*)d_in[5];
    const float* lin_b  = (const float*)d_in[6];
    const float* gate_w = (const float*)d_in[7];
    const float* gate_b = (const float*)d_in[8];
    const float* proj_w = (const float*)d_in[9];
    const float* ln_g   = (const float*)d_in[10];
    const float* ln_b   = (const float*)d_in[11];
    const float* sm_w   = (const float*)d_in[12];
    const float* sm_b   = (const float*)d_in[13];

    // ws: Cw 3.15MB | Hp (4 x bf16 partials) 25.17MB | linf 32KB | smf 16KB
    char* wsb = (char*)d_ws;
    _Float16* Cw   = (_Float16*)wsb;
    __bf16*   Hp   = (__bf16*)(wsb + (size_t)KCH * N3 * 2);
    __bf16*   linf = (__bf16*)(wsb + (size_t)KCH * N3 * 2
                                   + (size_t)KSPL * TOK * N3 * 2);
    __bf16*   smf  = linf + U_DIM * U_DIM;

    vsn_prep15<<<204, 256, 0, stream>>>(fw, fb, elu_w, gate_w, proj_w,
                                        lin_w, sm_w, Cw, linf, smf);
    vsn_gemm15<<<dim3(KSPL, TOK / BM), 512, 0, stream>>>(x, Cw, Hp);
    vsn_epi15<<<TOK / 32, 128, 0, stream>>>(x, Hp, linf, smf, elu_b, lin_b,
                                            gate_b, ln_g, ln_b, sm_b,
                                            (float*)d_out);
}

// Round 16
// 91.087 us; speedup vs baseline: 1.2132x; 1.2132x over previous
//
#include <hip/hip_runtime.h>
#include <hip/hip_bf16.h>
#include <math.h>

// Problem dims
#define TOK   8192
#define F_DIM 64
#define U_DIM 128
#define N3    384

// Chebyshev expansion
#define MCH   64
#define KCH   (F_DIM * MCH)      // 4096
#define RCH   6.0f

// GEMM tiling (R12-proven): KSPL=4, BM=64, BK=64, 256 thr (4 waves n-split)
#define BM    64
#define BK    64
#define KSPL  4
#define KRANGE (KCH / KSPL)      // 1024
#define NST   (KRANGE / BK)      // 16
#define NF    16
#define ASTR  72

typedef _Float16 h16x8 __attribute__((ext_vector_type(8)));
typedef __bf16   bf16x8 __attribute__((ext_vector_type(8)));
typedef float    f32x4 __attribute__((ext_vector_type(4)));

#define WG_SYNC() do {                                       \
    asm volatile("s_waitcnt lgkmcnt(0)" ::: "memory");       \
    __builtin_amdgcn_s_barrier();                            \
    __builtin_amdgcn_sched_barrier(0);                       \
} while (0)

__device__ __forceinline__ float bflo(unsigned u) { u <<= 16; return __builtin_bit_cast(float, u); }
__device__ __forceinline__ float bfhi(unsigned u) { u &= 0xffff0000u; return __builtin_bit_cast(float, u); }
__device__ __forceinline__ unsigned bfpack(float a, float b) {
    unsigned pa = (unsigned)__builtin_bit_cast(unsigned short, (__bf16)a);
    unsigned pb = (unsigned)__builtin_bit_cast(unsigned short, (__bf16)b);
    return pa | (pb << 16);
}

// ---------------------------------------------------------------------------
// Kernel 1 (R14/R15-validated): blocks 0..191 = (mat=bx>>6, f=bx&63):
// Chebyshev fit in-LDS (exact erf-gelu) + C-build, packed f16 GEMM layout.
// Blocks 192..203: pack lin_w/sm_w into MFMA B-frag order.
// ---------------------------------------------------------------------------
__global__ __launch_bounds__(256) void vsn_prep16(
    const float* __restrict__ fw,
    const float* __restrict__ fb,
    const float* __restrict__ elu_w,
    const float* __restrict__ gate_w,
    const float* __restrict__ proj_w,
    const float* __restrict__ lin_w,
    const float* __restrict__ sm_w,
    _Float16* __restrict__ Cw,
    __bf16* __restrict__ linf,
    __bf16* __restrict__ smf)
{
    const int t = threadIdx.x;
    const int bx = blockIdx.x;
    if (bx >= 192) {
        const int xb = bx - 192;
        if (xb < 8) {
#pragma unroll
            for (int i = 0; i < 8; ++i) {
                int idx = xb * 2048 + i * 256 + t;
                int j = idx & 7, l = (idx >> 3) & 63, q = idx >> 9;
                int ks = q >> 3, nj = q & 7;
                int k = ks * 32 + (l >> 4) * 8 + j;
                int n = nj * 16 + (l & 15);
                linf[idx] = (__bf16)lin_w[k * U_DIM + n];
            }
        } else {
            int sb = xb - 8;
#pragma unroll
            for (int i = 0; i < 8; ++i) {
                int idx = sb * 2048 + i * 256 + t;
                int j = idx & 7, l = (idx >> 3) & 63, q = idx >> 9;
                int ks = q >> 2, nj = q & 3;
                int k = ks * 32 + (l >> 4) * 8 + j;
                int n = nj * 16 + (l & 15);
                smf[idx] = (__bf16)sm_w[k * F_DIM + n];
            }
        }
        return;
    }

    __shared__ float ctab[MCH][67];
    __shared__ float g_lds[128][67];
    __shared__ float c_lds[128 * MCH];
    __shared__ float w_lds[32 * 128];

    const int f = bx & 63, mat = bx >> 6;
    const float* W = (mat == 0) ? elu_w : (mat == 1 ? gate_w : proj_w);
    const int kg0 = f * 128;

#pragma unroll
    for (int r = 0; r < 16; ++r) {
        int idx = r * 256 + t;
        int m = idx >> 6, i = idx & 63;
        float ang = 3.14159265358979f * (float)m * ((float)i + 0.5f) * (1.0f / 64.0f);
        ctab[m][i] = cosf(ang) * (2.0f / 64.0f) * (m == 0 ? 0.5f : 1.0f);
    }
    __syncthreads();

#pragma unroll 4
    for (int r = 0; r < 32; ++r) {
        int idx = r * 256 + t;
        int k = idx >> 6, i = idx & 63;
        float xi = ctab[1][i] * (RCH * 32.0f);
        float z = fmaf(fw[kg0 + k], xi, fb[kg0 + k]);
        g_lds[k][i] = 0.5f * z * (1.0f + erff(z * 0.70710678f));
    }
    __syncthreads();

    {
        const int k = t & 127, mh = t >> 7;
#pragma unroll 4
        for (int mm = 0; mm < 32; ++mm) {
            int m = mh * 32 + mm;
            float a = 0.f;
#pragma unroll
            for (int i = 0; i < 64; ++i)
                a = fmaf(g_lds[k][i], ctab[m][i], a);
            c_lds[k * MCH + m] = a;
        }
    }
    __syncthreads();

    const int n0 = (t & 31) * 4;
    const int mq = t >> 5;
    float acc[8][4];
#pragma unroll
    for (int e = 0; e < 8; ++e)
#pragma unroll
        for (int q = 0; q < 4; ++q) acc[e][q] = 0.f;

    for (int jc = 0; jc < 4; ++jc) {
        __syncthreads();
        {
            const f32x4* src = (const f32x4*)&W[(size_t)(kg0 + jc * 32) * U_DIM];
            f32x4* dst = (f32x4*)w_lds;
#pragma unroll
            for (int r = 0; r < 4; ++r) dst[r * 256 + t] = src[r * 256 + t];
        }
        __syncthreads();

#pragma unroll 4
        for (int jj = 0; jj < 32; ++jj) {
            const int j = jc * 32 + jj;
            f32x4 wv  = *(const f32x4*)&w_lds[jj * 128 + n0];
            f32x4 cv0 = *(const f32x4*)&c_lds[j * MCH + mq * 8];
            f32x4 cv1 = *(const f32x4*)&c_lds[j * MCH + mq * 8 + 4];
#pragma unroll
            for (int e = 0; e < 4; ++e)
#pragma unroll
                for (int q = 0; q < 4; ++q) {
                    acc[e][q]     = fmaf(cv0[e], wv[q], acc[e][q]);
                    acc[e + 4][q] = fmaf(cv1[e], wv[q], acc[e + 4][q]);
                }
        }
    }

    const int kb = mq >> 2;
    const int ko = (mq & 3) * 8;
#pragma unroll
    for (int q = 0; q < 4; ++q) {
        const int ng = mat * U_DIM + n0 + q;
        h16x8 v;
#pragma unroll
        for (int e = 0; e < 8; ++e) v[e] = (_Float16)acc[e][q];
        *(h16x8*)&Cw[(((size_t)(f * 2 + kb) * N3) + ng) * 32 + ko] = v;
    }
}

// ---------------------------------------------------------------------------
// Kernel 2 (R12's vsn_gemm12 verbatim — the 74.6 us config): Chebyshev GEMM.
// grid (KSPL=4, TOK/64=128), 256 thr (4 waves n-split 96, acc[4][6]),
// NST=16, f16 MFMA, ping-pong B prefetch, lgkm-only barriers.
// XCD id%8 in {s,s+4}: Cw slice (786KB) L2-resident per XCD.
// ---------------------------------------------------------------------------
__global__ __launch_bounds__(256, 2) void vsn_gemm16(
    const float* __restrict__ x,
    const _Float16* __restrict__ Cw,
    __bf16* __restrict__ Hp)
{
    __shared__ float     x_lds[BM][NF + 1];
    __shared__ _Float16  a_lds[2][BM][ASTR];

    const int t    = threadIdx.x;
    const int wave = t >> 6;
    const int lane = t & 63;
    const int s     = blockIdx.x;
    const int tok0  = blockIdx.y * BM;
    const int kbase = s * KRANGE;
    const int nbase = wave * 96;
    const int lr  = lane & 15;
    const int lk8 = (lane >> 4) * 8;

#pragma unroll
    for (int i = 0; i < (BM * NF) / 256; ++i) {
        int idx = i * 256 + t;
        int r = idx >> 4, c = idx & 15;
        x_lds[r][c] = x[(size_t)(tok0 + r) * F_DIM + (kbase >> 6) + c];
    }

    f32x4 acc[4][6];
#pragma unroll
    for (int i = 0; i < 4; ++i)
#pragma unroll
        for (int j = 0; j < 6; ++j)
            acc[i][j] = (f32x4){0.f, 0.f, 0.f, 0.f};

    const int m_a = t >> 2;          // 0..63: token row
    const int q   = t & 3;           // m-strip: m0 = q*16

    // A-tile: T_m(x~) for m in [q*16, q*16+16), feature = st
    auto cheb_write = [&](int st, int buf) {
        float xr = x_lds[m_a][st];
        float xt = fminf(fmaxf(xr * (1.0f / RCH), -1.0f), 1.0f);
        float x2 = xt + xt;
        float s1 = sqrtf(fmaxf(fmaf(-xt, xt, 1.0f), 0.0f));
        float T2 = fmaf(x2, xt, -1.0f),      S2 = x2 * s1;
        float T4 = fmaf(T2 + T2, T2, -1.0f), S4 = (T2 + T2) * S2;
        float T8 = fmaf(T4 + T4, T4, -1.0f), S8 = (T4 + T4) * S4;
        float T16 = fmaf(T8 + T8, T8, -1.0f), S16 = (T8 + T8) * S8;
        float T32 = fmaf(T16 + T16, T16, -1.0f), S32 = (T16 + T16) * S16;
        float T48 = fmaf(T32, T16, -S32 * S16);
        float S48 = fmaf(S32, T16, T32 * S16);
        float Ta = (q == 0) ? 1.0f : (q == 1) ? T16 : (q == 2) ? T32 : T48;
        float Sa = (q == 0) ? 0.0f : (q == 1) ? S16 : (q == 2) ? S32 : S48;
        float Tb = fmaf(xt, Ta, -Sa * s1);
        h16x8 o0, o1;
        float v0 = Ta, v1 = Tb;
        o0[0] = (_Float16)v0; o0[1] = (_Float16)v1;
#pragma unroll
        for (int i = 2; i < 8; ++i) {
            float v = fmaf(x2, v1, -v0); v0 = v1; v1 = v;
            o0[i] = (_Float16)v;
        }
#pragma unroll
        for (int i = 0; i < 8; ++i) {
            float v = fmaf(x2, v1, -v0); v0 = v1; v1 = v;
            o1[i] = (_Float16)v;
        }
        *(h16x8*)&a_lds[buf][m_a][q * 16]     = o0;
        *(h16x8*)&a_lds[buf][m_a][q * 16 + 8] = o1;
    };

    const _Float16* bb = Cw + (size_t)(kbase >> 5) * (N3 * 32)
                            + (nbase + lr) * 32 + lk8;
    auto loadB = [&](int st, int ksi, h16x8 (&dst)[6]) {
        const _Float16* p = bb + (size_t)(st * 2 + ksi) * (N3 * 32);
#pragma unroll
        for (int j = 0; j < 6; ++j)
            dst[j] = *(const h16x8*)(p + j * 512);
    };

    h16x8 bX[6], bY[6];

    WG_SYNC();
    cheb_write(0, 0);
    loadB(0, 0, bX);

    for (int st = 0; st < NST - 1; ++st) {
        const int cur = st & 1;
        WG_SYNC();
        loadB(st, 1, bY);
        cheb_write(st + 1, cur ^ 1);

        h16x8 af[4];
#pragma unroll
        for (int i = 0; i < 4; ++i)
            af[i] = *(const h16x8*)&a_lds[cur][i * 16 + lr][lk8];
#pragma unroll
        for (int i = 0; i < 4; ++i)
#pragma unroll
            for (int j = 0; j < 6; ++j)
                acc[i][j] = __builtin_amdgcn_mfma_f32_16x16x32_f16(
                    af[i], bX[j], acc[i][j], 0, 0, 0);

        loadB(st + 1, 0, bX);
#pragma unroll
        for (int i = 0; i < 4; ++i)
            af[i] = *(const h16x8*)&a_lds[cur][i * 16 + lr][32 + lk8];
#pragma unroll
        for (int i = 0; i < 4; ++i)
#pragma unroll
            for (int j = 0; j < 6; ++j)
                acc[i][j] = __builtin_amdgcn_mfma_f32_16x16x32_f16(
                    af[i], bY[j], acc[i][j], 0, 0, 0);
    }
    {
        const int cur = (NST - 1) & 1;
        WG_SYNC();
        loadB(NST - 1, 1, bY);
        h16x8 af[4];
#pragma unroll
        for (int i = 0; i < 4; ++i)
            af[i] = *(const h16x8*)&a_lds[cur][i * 16 + lr][lk8];
#pragma unroll
        for (int i = 0; i < 4; ++i)
#pragma unroll
            for (int j = 0; j < 6; ++j)
                acc[i][j] = __builtin_amdgcn_mfma_f32_16x16x32_f16(
                    af[i], bX[j], acc[i][j], 0, 0, 0);
#pragma unroll
        for (int i = 0; i < 4; ++i)
            af[i] = *(const h16x8*)&a_lds[cur][i * 16 + lr][32 + lk8];
#pragma unroll
        for (int i = 0; i < 4; ++i)
#pragma unroll
            for (int j = 0; j < 6; ++j)
                acc[i][j] = __builtin_amdgcn_mfma_f32_16x16x32_f16(
                    af[i], bY[j], acc[i][j], 0, 0, 0);
    }

    __bf16* Hs = Hp + (size_t)s * ((size_t)TOK * N3);
    const int r0 = (lane >> 4) * 4;
#pragma unroll
    for (int i = 0; i < 4; ++i)
#pragma unroll
        for (int j = 0; j < 6; ++j)
#pragma unroll
            for (int r = 0; r < 4; ++r)
                Hs[(size_t)(tok0 + i * 16 + r0 + r) * N3 + nbase + j * 16 + lr]
                    = (__bf16)acc[i][j][r];
}

// ---------------------------------------------------------------------------
// Kernel 3 (R13/R15 lean epilogue, validated). 256 WGs x 128 thr.
// ---------------------------------------------------------------------------
__global__ __launch_bounds__(128) void vsn_epi16(
    const float* __restrict__ x,
    const __bf16* __restrict__ Hp,
    const __bf16* __restrict__ linf,
    const __bf16* __restrict__ smf,
    const float* __restrict__ elu_b,
    const float* __restrict__ lin_b,
    const float* __restrict__ gate_b,
    const float* __restrict__ ln_g,
    const float* __restrict__ ln_b,
    const float* __restrict__ sm_b,
    float* __restrict__ out)
{
    __shared__ __bf16   h1_lds[2][16][136];
    __shared__ unsigned g_lds[2][16][66];
    __shared__ float    p_lds[2][16][132];

    const int t = threadIdx.x, w = t >> 6, lane = t & 63;
    const int tokb = blockIdx.x * 32 + w * 16;

    const float2 eb = *(const float2*)&elu_b[2 * lane];
    const float2 gb = *(const float2*)&gate_b[2 * lane];
#pragma unroll 4
    for (int tk = 0; tk < 16; ++tk) {
        const unsigned short* base =
            (const unsigned short*)Hp + (size_t)(tokb + tk) * N3;
        float a0 = 0.f, a1 = 0.f, g0 = 0.f, g1 = 0.f, p0 = 0.f, p1 = 0.f;
#pragma unroll
        for (int s = 0; s < KSPL; ++s) {
            const unsigned short* bs = base + (size_t)s * TOK * N3;
            unsigned ua = *(const unsigned*)(bs + 2 * lane);
            unsigned ug = *(const unsigned*)(bs + 128 + 2 * lane);
            unsigned up = *(const unsigned*)(bs + 256 + 2 * lane);
            a0 += bflo(ua); a1 += bfhi(ua);
            g0 += bflo(ug); g1 += bfhi(ug);
            p0 += bflo(up); p1 += bfhi(up);
        }
        float e0 = a0 + eb.x, e1 = a1 + eb.y;
        float h10 = (e0 > 0.f) ? e0 : expm1f(e0);
        float h11 = (e1 > 0.f) ? e1 : expm1f(e1);
        *(unsigned*)((char*)&h1_lds[w][tk][0] + 4 * lane) = bfpack(h10, h11);
        float ga  = 1.f / (1.f + __expf(-(g0 + gb.x)));
        float gbv = 1.f / (1.f + __expf(-(g1 + gb.y)));
        g_lds[w][tk][lane] = bfpack(ga, gbv);
        p_lds[w][tk][2 * lane]     = p0;
        p_lds[w][tk][2 * lane + 1] = p1;
    }
    __syncthreads();

    const int c0 = lane & 15;
    const int rg = lane >> 4;

    f32x4 acc[8];
#pragma unroll
    for (int nj = 0; nj < 8; ++nj) acc[nj] = (f32x4){0.f, 0.f, 0.f, 0.f};
#pragma unroll
    for (int ks = 0; ks < 4; ++ks) {
        bf16x8 af = *(const bf16x8*)&h1_lds[w][c0][ks * 32 + rg * 8];
#pragma unroll
        for (int nj = 0; nj < 8; ++nj) {
            bf16x8 bf = *(const bf16x8*)&linf[((ks * 8 + nj) * 64 + lane) * 8];
            acc[nj] = __builtin_amdgcn_mfma_f32_16x16x32_bf16(af, bf, acc[nj], 0, 0, 0);
        }
    }

    float h[8][4];
#pragma unroll
    for (int nj = 0; nj < 8; ++nj) {
        float lb = lin_b[c0 + 16 * nj];
        int colh = (c0 + 16 * nj) >> 1;
        int odd  = c0 & 1;
#pragma unroll
        for (int r = 0; r < 4; ++r) {
            int tokr = rg * 4 + r;
            float h2 = acc[nj][r] + lb;
            unsigned gu = g_lds[w][tokr][colh];
            float g = odd ? bfhi(gu) : bflo(gu);
            float p = p_lds[w][tokr][c0 + 16 * nj];
            h[nj][r] = fmaf(g, h2, p);
        }
    }

    float mu[4], rstd[4];
#pragma unroll
    for (int r = 0; r < 4; ++r) {
        float s = 0.f;
#pragma unroll
        for (int nj = 0; nj < 8; ++nj) s += h[nj][r];
        s += __shfl_xor(s, 1); s += __shfl_xor(s, 2);
        s += __shfl_xor(s, 4); s += __shfl_xor(s, 8);
        mu[r] = s * (1.0f / 128.0f);
        float v = 0.f;
#pragma unroll
        for (int nj = 0; nj < 8; ++nj) {
            float d = h[nj][r] - mu[r];
            v = fmaf(d, d, v);
        }
        v += __shfl_xor(v, 1); v += __shfl_xor(v, 2);
        v += __shfl_xor(v, 4); v += __shfl_xor(v, 8);
        rstd[r] = rsqrtf(v * (1.0f / 128.0f) + 1e-3f);
    }

#pragma unroll
    for (int nj = 0; nj < 8; ++nj) {
        int col = c0 + 16 * nj;
        float lg = ln_g[col], lb = ln_b[col];
#pragma unroll
        for (int r = 0; r < 4; ++r) {
            float y = fmaf((h[nj][r] - mu[r]) * rstd[r], lg, lb);
            h1_lds[w][rg * 4 + r][col] = (__bf16)y;
        }
    }

    f32x4 acc2[4];
#pragma unroll
    for (int nj = 0; nj < 4; ++nj) acc2[nj] = (f32x4){0.f, 0.f, 0.f, 0.f};
#pragma unroll
    for (int ks = 0; ks < 4; ++ks) {
        bf16x8 af = *(const bf16x8*)&h1_lds[w][c0][ks * 32 + rg * 8];
#pragma unroll
        for (int nj = 0; nj < 4; ++nj) {
            bf16x8 bf = *(const bf16x8*)&smf[((ks * 4 + nj) * 64 + lane) * 8];
            acc2[nj] = __builtin_amdgcn_mfma_f32_16x16x32_bf16(af, bf, acc2[nj], 0, 0, 0);
        }
    }

    float lgt[4][4];
#pragma unroll
    for (int nj = 0; nj < 4; ++nj) {
        float sb = sm_b[c0 + 16 * nj];
#pragma unroll
        for (int r = 0; r < 4; ++r) lgt[nj][r] = acc2[nj][r] + sb;
    }
#pragma unroll
    for (int r = 0; r < 4; ++r) {
        float mx = fmaxf(fmaxf(lgt[0][r], lgt[1][r]), fmaxf(lgt[2][r], lgt[3][r]));
        mx = fmaxf(mx, __shfl_xor(mx, 1)); mx = fmaxf(mx, __shfl_xor(mx, 2));
        mx = fmaxf(mx, __shfl_xor(mx, 4)); mx = fmaxf(mx, __shfl_xor(mx, 8));
        float ex[4], se = 0.f;
#pragma unroll
        for (int nj = 0; nj < 4; ++nj) {
            ex[nj] = __expf(lgt[nj][r] - mx);
            se += ex[nj];
        }
        se += __shfl_xor(se, 1); se += __shfl_xor(se, 2);
        se += __shfl_xor(se, 4); se += __shfl_xor(se, 8);
        float inv = 1.0f / se;
        int tok = tokb + rg * 4 + r;
#pragma unroll
        for (int nj = 0; nj < 4; ++nj) {
            int f = c0 + 16 * nj;
            float wgt = ex[nj] * inv;
            float xv = x[(size_t)tok * F_DIM + f];
            out[(size_t)tok * F_DIM + f] = xv * wgt;
            out[(size_t)TOK * F_DIM + (size_t)tok * F_DIM + f] = wgt;
        }
    }
}

// ---------------------------------------------------------------------------
extern "C" void kernel_launch(void* const* d_in, const int* in_sizes, int n_in,
                              void* d_out, int out_size, void* d_ws, size_t ws_size,
                              hipStream_t stream)
{
    const float* x      = (const float*)d_in[0];
    const float* fw     = (const float*)d_in[1];
    const float* fb     = (const float*)d_in[2];
    const float* elu_w  = (const float*)d_in[3];
    const float* elu_b  = (const float*)d_in[4];
    const float* lin_w  = (const float*)d_in[5];
    const float* lin_b  = (const float*)d_in[6];
    const float* gate_w = (const float*)d_in[7];
    const float* gate_b = (const float*)d_in[8];
    const float* proj_w = (const float*)d_in[9];
    const float* ln_g   = (const float*)d_in[10];
    const float* ln_b   = (const float*)d_in[11];
    const float* sm_w   = (const float*)d_in[12];
    const float* sm_b   = (const float*)d_in[13];

    // ws: Cw 3.15MB | Hp (4 x bf16 partials) 25.17MB | linf 32KB | smf 16KB
    char* wsb = (char*)d_ws;
    _Float16* Cw   = (_Float16*)wsb;
    __bf16*   Hp   = (__bf16*)(wsb + (size_t)KCH * N3 * 2);
    __bf16*   linf = (__bf16*)(wsb + (size_t)KCH * N3 * 2
                                   + (size_t)KSPL * TOK * N3 * 2);
    __bf16*   smf  = linf + U_DIM * U_DIM;

    vsn_prep16<<<204, 256, 0, stream>>>(fw, fb, elu_w, gate_w, proj_w,
                                        lin_w, sm_w, Cw, linf, smf);
    vsn_gemm16<<<dim3(KSPL, TOK / BM), 256, 0, stream>>>(x, Cw, Hp);
    vsn_epi16<<<TOK / 32, 128, 0, stream>>>(x, Hp, linf, smf, elu_b, lin_b,
                                            gate_b, ln_g, ln_b, sm_b,
                                            (float*)d_out);
}

// Round 17
// 74.901 us; speedup vs baseline: 1.4754x; 1.2161x over previous
//
#include <hip/hip_runtime.h>
#include <hip/hip_bf16.h>
#include <math.h>

// Problem dims
#define TOK   8192
#define F_DIM 64
#define U_DIM 128
#define N3    384

// Chebyshev expansion: K = 64 features x 64 coeffs
#define MCH   64
#define KCH   (F_DIM * MCH)      // 4096
#define RCH   6.0f

// GEMM tiling (R12 pipeline): BK=64 = one feature's m-range
#define BM    64
#define BK    64
#define KSPL  4
#define KRANGE (KCH / KSPL)      // 1024 (16 features)
#define NST   (KRANGE / BK)      // 16
#define NF    16                 // features per split
#define ASTR  72

typedef _Float16 h16x8 __attribute__((ext_vector_type(8)));
typedef __bf16   bf16x8 __attribute__((ext_vector_type(8)));
typedef float    f32x4 __attribute__((ext_vector_type(4)));

#define WG_SYNC() do {                                       \
    asm volatile("s_waitcnt lgkmcnt(0)" ::: "memory");       \
    __builtin_amdgcn_s_barrier();                            \
    __builtin_amdgcn_sched_barrier(0);                       \
} while (0)

__device__ __forceinline__ float bflo(unsigned u) { u <<= 16; return __builtin_bit_cast(float, u); }
__device__ __forceinline__ float bfhi(unsigned u) { u &= 0xffff0000u; return __builtin_bit_cast(float, u); }
__device__ __forceinline__ unsigned bfpack(float a, float b) {
    unsigned pa = (unsigned)__builtin_bit_cast(unsigned short, (__bf16)a);
    unsigned pb = (unsigned)__builtin_bit_cast(unsigned short, (__bf16)b);
    return pa | (pb << 16);
}

// ---------------------------------------------------------------------------
// Kernel P1: blocks 0..255: Chebyshev fit, 32 k's per block, LDS-cooperative.
//   c[k][m] = (2/64)·sum_i gelu(w_k x_i + b_k)·cos(pi m (i+.5)/64), m=0 halved,
//   nodes x_i = R·cos(pi(i+.5)/64). Exact erf-gelu.
// Blocks 256..267: pack lin_w/sm_w into MFMA B-frag order.
// ---------------------------------------------------------------------------
__global__ __launch_bounds__(256) void vsn_prep17(
    const float* __restrict__ fw,
    const float* __restrict__ fb,
    const float* __restrict__ lin_w,
    const float* __restrict__ sm_w,
    float* __restrict__ c_ws,
    __bf16* __restrict__ linf,
    __bf16* __restrict__ smf)
{
    const int t = threadIdx.x;
    const int bx = blockIdx.x;
    if (bx >= 256) {
        const int xb = bx - 256;
        if (xb < 8) {
#pragma unroll
            for (int i = 0; i < 8; ++i) {
                int idx = xb * 2048 + i * 256 + t;
                int j = idx & 7, l = (idx >> 3) & 63, q = idx >> 9;
                int ks = q >> 3, nj = q & 7;
                int k = ks * 32 + (l >> 4) * 8 + j;
                int n = nj * 16 + (l & 15);
                linf[idx] = (__bf16)lin_w[k * U_DIM + n];
            }
        } else {
            int sb = xb - 8;
#pragma unroll
            for (int i = 0; i < 8; ++i) {
                int idx = sb * 2048 + i * 256 + t;
                int j = idx & 7, l = (idx >> 3) & 63, q = idx >> 9;
                int ks = q >> 2, nj = q & 3;
                int k = ks * 32 + (l >> 4) * 8 + j;
                int n = nj * 16 + (l & 15);
                smf[idx] = (__bf16)sm_w[k * F_DIM + n];
            }
        }
        return;
    }

    __shared__ float ctab[MCH][67];   // [m][i], includes 2/64 and m==0 half
    __shared__ float g_lds[32][67];   // [k][i]
    const int k0 = bx * 32;

#pragma unroll
    for (int r = 0; r < 16; ++r) {
        int idx = r * 256 + t;
        int m = idx >> 6, i = idx & 63;
        float ang = 3.14159265358979f * (float)m * ((float)i + 0.5f) * (1.0f / 64.0f);
        ctab[m][i] = cosf(ang) * (2.0f / 64.0f) * (m == 0 ? 0.5f : 1.0f);
    }
    __syncthreads();

    // g: 32 k x 64 i, 8 evals/thread
#pragma unroll
    for (int r = 0; r < 8; ++r) {
        int idx = r * 256 + t;
        int k = idx >> 6, i = idx & 63;
        float xi = ctab[1][i] * (RCH * 32.0f);     // = R*cos(pi(i+.5)/64)
        float z = fmaf(fw[k0 + k], xi, fb[k0 + k]);
        g_lds[k][i] = 0.5f * z * (1.0f + erff(z * 0.70710678f));
    }
    __syncthreads();

    // dots: thread = (k = t>>3, m0 = (t&7)*8), 8 dots of 64
    const int k = t >> 3, m0 = (t & 7) * 8;
    float a[8] = {0.f, 0.f, 0.f, 0.f, 0.f, 0.f, 0.f, 0.f};
    for (int i = 0; i < 64; ++i) {
        float gval = g_lds[k][i];
#pragma unroll
        for (int mm = 0; mm < 8; ++mm)
            a[mm] = fmaf(gval, ctab[m0 + mm][i], a[mm]);
    }
    float* dst = &c_ws[(size_t)(k0 + k) * MCH + m0];
#pragma unroll
    for (int mm = 0; mm < 8; ++mm) dst[mm] = a[mm];
}

// ---------------------------------------------------------------------------
// Kernel P2: C-build, LDS-tiled. Cw[f*64+m][n] = sum_j c[f*128+j][m]·W[..j][n],
// f32 accumulate, written in the GEMM's packed f16 layout.
// grid (64 f, 3 mat) x 256 thr.
// ---------------------------------------------------------------------------
__global__ __launch_bounds__(256) void vsn_cbuild17(
    const float* __restrict__ c_ws,
    const float* __restrict__ elu_w,
    const float* __restrict__ gate_w,
    const float* __restrict__ proj_w,
    _Float16* __restrict__ Cw)
{
    __shared__ float c_lds[128 * MCH];   // 32 KB  [j][m]
    __shared__ float w_lds[32 * 128];    // 16 KB  [jj][n]
    const int f = blockIdx.x, mat = blockIdx.y;
    const float* W = (mat == 0) ? elu_w : (mat == 1 ? gate_w : proj_w);
    const int t = threadIdx.x;

    {   // stage c_f (coalesced f32x4)
        const f32x4* src = (const f32x4*)&c_ws[(size_t)f * 128 * MCH];
        f32x4* dst = (f32x4*)c_lds;
#pragma unroll
        for (int i = 0; i < 8; ++i) dst[i * 256 + t] = src[i * 256 + t];
    }

    const int n0 = (t & 31) * 4;
    const int mq = t >> 5;
    float acc[8][4];
#pragma unroll
    for (int e = 0; e < 8; ++e)
#pragma unroll
        for (int q = 0; q < 4; ++q) acc[e][q] = 0.f;

    for (int jc = 0; jc < 4; ++jc) {
        __syncthreads();    // w_lds free (and c_lds staged on first pass)
        {
            const f32x4* src = (const f32x4*)&W[(size_t)(f * 128 + jc * 32) * U_DIM];
            f32x4* dst = (f32x4*)w_lds;
#pragma unroll
            for (int r = 0; r < 4; ++r) dst[r * 256 + t] = src[r * 256 + t];
        }
        __syncthreads();

#pragma unroll 4
        for (int jj = 0; jj < 32; ++jj) {
            const int j = jc * 32 + jj;
            f32x4 wv  = *(const f32x4*)&w_lds[jj * 128 + n0];
            f32x4 cv0 = *(const f32x4*)&c_lds[j * MCH + mq * 8];
            f32x4 cv1 = *(const f32x4*)&c_lds[j * MCH + mq * 8 + 4];
#pragma unroll
            for (int e = 0; e < 4; ++e)
#pragma unroll
                for (int q = 0; q < 4; ++q) {
                    acc[e][q]     = fmaf(cv0[e], wv[q], acc[e][q]);
                    acc[e + 4][q] = fmaf(cv1[e], wv[q], acc[e + 4][q]);
                }
        }
    }

    // packed layout: Cw[((f*2 + m>>5)*384 + ng)*32 + (m&31)], m = mq*8+e
    const int kb  = mq >> 2;
    const int ko  = (mq & 3) * 8;
#pragma unroll
    for (int q = 0; q < 4; ++q) {
        const int ng = mat * U_DIM + n0 + q;
        h16x8 v;
#pragma unroll
        for (int e = 0; e < 8; ++e) v[e] = (_Float16)acc[e][q];
        *(h16x8*)&Cw[(((size_t)(f * 2 + kb) * N3) + ng) * 32 + ko] = v;
    }
}

// ---------------------------------------------------------------------------
// Kernel 3: Chebyshev GEMM (R12-proven config). grid (KSPL=4, TOK/64=128),
// 256 thr (4 waves n-split 96, acc[4][6]), NST=16, f16 MFMA, ping-pong B.
// XCD id%8 in {s,s+4}: Cw slice (786KB) L2-resident per XCD.
// ---------------------------------------------------------------------------
__global__ __launch_bounds__(256, 2) void vsn_gemm17(
    const float* __restrict__ x,
    const _Float16* __restrict__ Cw,
    __bf16* __restrict__ Hp)
{
    __shared__ float     x_lds[BM][NF + 1];
    __shared__ _Float16  a_lds[2][BM][ASTR];

    const int t    = threadIdx.x;
    const int wave = t >> 6;
    const int lane = t & 63;
    const int s     = blockIdx.x;
    const int tok0  = blockIdx.y * BM;
    const int kbase = s * KRANGE;
    const int nbase = wave * 96;
    const int lr  = lane & 15;
    const int lk8 = (lane >> 4) * 8;

#pragma unroll
    for (int i = 0; i < (BM * NF) / 256; ++i) {
        int idx = i * 256 + t;
        int r = idx >> 4, c = idx & 15;
        x_lds[r][c] = x[(size_t)(tok0 + r) * F_DIM + (kbase >> 6) + c];
    }

    f32x4 acc[4][6];
#pragma unroll
    for (int i = 0; i < 4; ++i)
#pragma unroll
        for (int j = 0; j < 6; ++j)
            acc[i][j] = (f32x4){0.f, 0.f, 0.f, 0.f};

    const int m_a = t >> 2;
    const int q   = t & 3;
    const int kk  = q * 16;

    auto cheb_write = [&](int st, int buf) {
        float xr = x_lds[m_a][st];
        float xt = fminf(fmaxf(xr * (1.0f / RCH), -1.0f), 1.0f);
        float x2 = xt + xt;
        float s1 = sqrtf(fmaxf(fmaf(-xt, xt, 1.0f), 0.0f));
        float T2 = fmaf(x2, xt, -1.0f),    S2 = x2 * s1;
        float T4 = fmaf(T2 + T2, T2, -1.0f), S4 = (T2 + T2) * S2;
        float T8 = fmaf(T4 + T4, T4, -1.0f), S8 = (T4 + T4) * S4;
        float T16 = fmaf(T8 + T8, T8, -1.0f), S16 = (T8 + T8) * S8;
        float T32 = fmaf(T16 + T16, T16, -1.0f), S32 = (T16 + T16) * S16;
        float T48 = fmaf(T32, T16, -S32 * S16);
        float S48 = fmaf(S32, T16, T32 * S16);
        float Ta = (q == 0) ? 1.0f : (q == 1) ? T16 : (q == 2) ? T32 : T48;
        float Sa = (q == 0) ? 0.0f : (q == 1) ? S16 : (q == 2) ? S32 : S48;
        float Tb = fmaf(xt, Ta, -Sa * s1);
        h16x8 o0, o1;
        float v0 = Ta, v1 = Tb;
        o0[0] = (_Float16)v0; o0[1] = (_Float16)v1;
#pragma unroll
        for (int i = 2; i < 8; ++i) {
            float v = fmaf(x2, v1, -v0); v0 = v1; v1 = v;
            o0[i] = (_Float16)v;
        }
#pragma unroll
        for (int i = 0; i < 8; ++i) {
            float v = fmaf(x2, v1, -v0); v0 = v1; v1 = v;
            o1[i] = (_Float16)v;
        }
        *(h16x8*)&a_lds[buf][m_a][kk]     = o0;
        *(h16x8*)&a_lds[buf][m_a][kk + 8] = o1;
    };

    const _Float16* bb = Cw + (size_t)(kbase >> 5) * (N3 * 32)
                            + (nbase + lr) * 32 + lk8;
    auto loadB = [&](int st, int ksi, h16x8 (&dst)[6]) {
        const _Float16* p = bb + (size_t)(st * 2 + ksi) * (N3 * 32);
#pragma unroll
        for (int j = 0; j < 6; ++j)
            dst[j] = *(const h16x8*)(p + j * 512);
    };

    h16x8 bX[6], bY[6];

    WG_SYNC();
    cheb_write(0, 0);
    loadB(0, 0, bX);

    for (int st = 0; st < NST - 1; ++st) {
        const int cur = st & 1;
        WG_SYNC();
        loadB(st, 1, bY);
        cheb_write(st + 1, cur ^ 1);

        h16x8 af[4];
#pragma unroll
        for (int i = 0; i < 4; ++i)
            af[i] = *(const h16x8*)&a_lds[cur][i * 16 + lr][lk8];
#pragma unroll
        for (int i = 0; i < 4; ++i)
#pragma unroll
            for (int j = 0; j < 6; ++j)
                acc[i][j] = __builtin_amdgcn_mfma_f32_16x16x32_f16(
                    af[i], bX[j], acc[i][j], 0, 0, 0);

        loadB(st + 1, 0, bX);
#pragma unroll
        for (int i = 0; i < 4; ++i)
            af[i] = *(const h16x8*)&a_lds[cur][i * 16 + lr][32 + lk8];
#pragma unroll
        for (int i = 0; i < 4; ++i)
#pragma unroll
            for (int j = 0; j < 6; ++j)
                acc[i][j] = __builtin_amdgcn_mfma_f32_16x16x32_f16(
                    af[i], bY[j], acc[i][j], 0, 0, 0);
    }
    {
        const int cur = (NST - 1) & 1;
        WG_SYNC();
        loadB(NST - 1, 1, bY);
        h16x8 af[4];
#pragma unroll
        for (int i = 0; i < 4; ++i)
            af[i] = *(const h16x8*)&a_lds[cur][i * 16 + lr][lk8];
#pragma unroll
        for (int i = 0; i < 4; ++i)
#pragma unroll
            for (int j = 0; j < 6; ++j)
                acc[i][j] = __builtin_amdgcn_mfma_f32_16x16x32_f16(
                    af[i], bX[j], acc[i][j], 0, 0, 0);
#pragma unroll
        for (int i = 0; i < 4; ++i)
            af[i] = *(const h16x8*)&a_lds[cur][i * 16 + lr][32 + lk8];
#pragma unroll
        for (int i = 0; i < 4; ++i)
#pragma unroll
            for (int j = 0; j < 6; ++j)
                acc[i][j] = __builtin_amdgcn_mfma_f32_16x16x32_f16(
                    af[i], bY[j], acc[i][j], 0, 0, 0);
    }

    __bf16* Hs = Hp + (size_t)s * ((size_t)TOK * N3);
    const int r0 = (lane >> 4) * 4;
#pragma unroll
    for (int i = 0; i < 4; ++i)
#pragma unroll
        for (int j = 0; j < 6; ++j)
#pragma unroll
            for (int r = 0; r < 4; ++r)
                Hs[(size_t)(tok0 + i * 16 + r0 + r) * N3 + nbase + j * 16 + lr]
                    = (__bf16)acc[i][j][r];
}

// ---------------------------------------------------------------------------
// Kernel 4: MFMA epilogue (R12/R9-validated, staged-weight variant).
// 256 WGs x 128 thr; 16 tok/wave.
// ---------------------------------------------------------------------------
__global__ __launch_bounds__(128) void vsn_epi17(
    const float* __restrict__ x,
    const __bf16* __restrict__ Hp,
    const __bf16* __restrict__ linf,
    const __bf16* __restrict__ smf,
    const float* __restrict__ elu_b,
    const float* __restrict__ lin_b,
    const float* __restrict__ gate_b,
    const float* __restrict__ ln_g,
    const float* __restrict__ ln_b,
    const float* __restrict__ sm_b,
    float* __restrict__ out)
{
    __shared__ __bf16 linf_lds[32 * 512];
    __shared__ __bf16 smf_lds[16 * 512];
    __shared__ __bf16 h1_lds[2][16][136];
    __shared__ float  g_lds[2][16][132];
    __shared__ float  p_lds[2][16][132];

    const int t = threadIdx.x, w = t >> 6, lane = t & 63;
    const int tokb = blockIdx.x * 32 + w * 16;

    {
        const uint4* s4 = (const uint4*)linf;
        uint4* d4 = (uint4*)linf_lds;
#pragma unroll
        for (int i = 0; i < 16; ++i) d4[i * 128 + t] = s4[i * 128 + t];
        const uint4* s2 = (const uint4*)smf;
        uint4* d2 = (uint4*)smf_lds;
#pragma unroll
        for (int i = 0; i < 8; ++i) d2[i * 128 + t] = s2[i * 128 + t];
    }

    const float2 eb = *(const float2*)&elu_b[2 * lane];
    const float2 gb = *(const float2*)&gate_b[2 * lane];
#pragma unroll 4
    for (int tk = 0; tk < 16; ++tk) {
        const unsigned short* base =
            (const unsigned short*)Hp + (size_t)(tokb + tk) * N3;
        float a0 = 0.f, a1 = 0.f, g0 = 0.f, g1 = 0.f, p0 = 0.f, p1 = 0.f;
#pragma unroll
        for (int s = 0; s < KSPL; ++s) {
            const unsigned short* bs = base + (size_t)s * TOK * N3;
            unsigned ua = *(const unsigned*)(bs + 2 * lane);
            unsigned ug = *(const unsigned*)(bs + 128 + 2 * lane);
            unsigned up = *(const unsigned*)(bs + 256 + 2 * lane);
            a0 += bflo(ua); a1 += bfhi(ua);
            g0 += bflo(ug); g1 += bfhi(ug);
            p0 += bflo(up); p1 += bfhi(up);
        }
        float e0 = a0 + eb.x, e1 = a1 + eb.y;
        float h10 = (e0 > 0.f) ? e0 : expm1f(e0);
        float h11 = (e1 > 0.f) ? e1 : expm1f(e1);
        *(unsigned*)((char*)&h1_lds[w][tk][0] + 4 * lane) = bfpack(h10, h11);
        g_lds[w][tk][2 * lane]     = 1.f / (1.f + __expf(-(g0 + gb.x)));
        g_lds[w][tk][2 * lane + 1] = 1.f / (1.f + __expf(-(g1 + gb.y)));
        p_lds[w][tk][2 * lane]     = p0;
        p_lds[w][tk][2 * lane + 1] = p1;
    }
    __syncthreads();

    const int c0 = lane & 15;
    const int rg = lane >> 4;

    f32x4 acc[8];
#pragma unroll
    for (int nj = 0; nj < 8; ++nj) acc[nj] = (f32x4){0.f, 0.f, 0.f, 0.f};
#pragma unroll
    for (int ks = 0; ks < 4; ++ks) {
        bf16x8 af = *(const bf16x8*)&h1_lds[w][c0][ks * 32 + rg * 8];
#pragma unroll
        for (int nj = 0; nj < 8; ++nj) {
            bf16x8 bf = *(const bf16x8*)&linf_lds[((ks * 8 + nj) * 64 + lane) * 8];
            acc[nj] = __builtin_amdgcn_mfma_f32_16x16x32_bf16(af, bf, acc[nj], 0, 0, 0);
        }
    }

    float h[8][4];
#pragma unroll
    for (int nj = 0; nj < 8; ++nj) {
        float lb = lin_b[c0 + 16 * nj];
#pragma unroll
        for (int r = 0; r < 4; ++r) {
            int tokr = rg * 4 + r;
            float h2 = acc[nj][r] + lb;
            float g  = g_lds[w][tokr][c0 + 16 * nj];
            float p  = p_lds[w][tokr][c0 + 16 * nj];
            h[nj][r] = fmaf(g, h2, p);
        }
    }

    float mu[4], rstd[4];
#pragma unroll
    for (int r = 0; r < 4; ++r) {
        float s = 0.f;
#pragma unroll
        for (int nj = 0; nj < 8; ++nj) s += h[nj][r];
        s += __shfl_xor(s, 1); s += __shfl_xor(s, 2);
        s += __shfl_xor(s, 4); s += __shfl_xor(s, 8);
        mu[r] = s * (1.0f / 128.0f);
        float v = 0.f;
#pragma unroll
        for (int nj = 0; nj < 8; ++nj) {
            float d = h[nj][r] - mu[r];
            v = fmaf(d, d, v);
        }
        v += __shfl_xor(v, 1); v += __shfl_xor(v, 2);
        v += __shfl_xor(v, 4); v += __shfl_xor(v, 8);
        rstd[r] = rsqrtf(v * (1.0f / 128.0f) + 1e-3f);
    }

#pragma unroll
    for (int nj = 0; nj < 8; ++nj) {
        int col = c0 + 16 * nj;
        float lg = ln_g[col], lb = ln_b[col];
#pragma unroll
        for (int r = 0; r < 4; ++r) {
            float y = fmaf((h[nj][r] - mu[r]) * rstd[r], lg, lb);
            h1_lds[w][rg * 4 + r][col] = (__bf16)y;
        }
    }

    f32x4 acc2[4];
#pragma unroll
    for (int nj = 0; nj < 4; ++nj) acc2[nj] = (f32x4){0.f, 0.f, 0.f, 0.f};
#pragma unroll
    for (int ks = 0; ks < 4; ++ks) {
        bf16x8 af = *(const bf16x8*)&h1_lds[w][c0][ks * 32 + rg * 8];
#pragma unroll
        for (int nj = 0; nj < 4; ++nj) {
            bf16x8 bf = *(const bf16x8*)&smf_lds[((ks * 4 + nj) * 64 + lane) * 8];
            acc2[nj] = __builtin_amdgcn_mfma_f32_16x16x32_bf16(af, bf, acc2[nj], 0, 0, 0);
        }
    }

    float lgt[4][4];
#pragma unroll
    for (int nj = 0; nj < 4; ++nj) {
        float sb = sm_b[c0 + 16 * nj];
#pragma unroll
        for (int r = 0; r < 4; ++r) lgt[nj][r] = acc2[nj][r] + sb;
    }
#pragma unroll
    for (int r = 0; r < 4; ++r) {
        float mx = fmaxf(fmaxf(lgt[0][r], lgt[1][r]), fmaxf(lgt[2][r], lgt[3][r]));
        mx = fmaxf(mx, __shfl_xor(mx, 1)); mx = fmaxf(mx, __shfl_xor(mx, 2));
        mx = fmaxf(mx, __shfl_xor(mx, 4)); mx = fmaxf(mx, __shfl_xor(mx, 8));
        float ex[4], se = 0.f;
#pragma unroll
        for (int nj = 0; nj < 4; ++nj) {
            ex[nj] = __expf(lgt[nj][r] - mx);
            se += ex[nj];
        }
        se += __shfl_xor(se, 1); se += __shfl_xor(se, 2);
        se += __shfl_xor(se, 4); se += __shfl_xor(se, 8);
        float inv = 1.0f / se;
        int tok = tokb + rg * 4 + r;
#pragma unroll
        for (int nj = 0; nj < 4; ++nj) {
            int f = c0 + 16 * nj;
            float wgt = ex[nj] * inv;
            float xv = x[(size_t)tok * F_DIM + f];
            out[(size_t)tok * F_DIM + f] = xv * wgt;
            out[(size_t)TOK * F_DIM + (size_t)tok * F_DIM + f] = wgt;
        }
    }
}

// ---------------------------------------------------------------------------
extern "C" void kernel_launch(void* const* d_in, const int* in_sizes, int n_in,
                              void* d_out, int out_size, void* d_ws, size_t ws_size,
                              hipStream_t stream)
{
    const float* x      = (const float*)d_in[0];
    const float* fw     = (const float*)d_in[1];
    const float* fb     = (const float*)d_in[2];
    const float* elu_w  = (const float*)d_in[3];
    const float* elu_b  = (const float*)d_in[4];
    const float* lin_w  = (const float*)d_in[5];
    const float* lin_b  = (const float*)d_in[6];
    const float* gate_w = (const float*)d_in[7];
    const float* gate_b = (const float*)d_in[8];
    const float* proj_w = (const float*)d_in[9];
    const float* ln_g   = (const float*)d_in[10];
    const float* ln_b   = (const float*)d_in[11];
    const float* sm_w   = (const float*)d_in[12];
    const float* sm_b   = (const float*)d_in[13];

    // ws: Cw 3.15MB | Hp 25.17MB | linf 32KB | smf 16KB | c_ws 2MB
    char* wsb = (char*)d_ws;
    _Float16* Cw   = (_Float16*)wsb;
    __bf16*   Hp   = (__bf16*)(wsb + (size_t)KCH * N3 * 2);
    __bf16*   linf = (__bf16*)(wsb + (size_t)KCH * N3 * 2
                                   + (size_t)KSPL * TOK * N3 * 2);
    __bf16*   smf  = linf + U_DIM * U_DIM;
    float*    c_ws = (float*)((char*)smf + U_DIM * F_DIM * 2);

    vsn_prep17<<<268, 256, 0, stream>>>(fw, fb, lin_w, sm_w, c_ws, linf, smf);
    vsn_cbuild17<<<dim3(64, 3), 256, 0, stream>>>(c_ws, elu_w, gate_w, proj_w, Cw);
    vsn_gemm17<<<dim3(KSPL, TOK / BM), 256, 0, stream>>>(x, Cw, Hp);
    vsn_epi17<<<TOK / 32, 128, 0, stream>>>(x, Hp, linf, smf, elu_b, lin_b,
                                            gate_b, ln_g, ln_b, sm_b,
                                            (float*)d_out);
}

// Round 18
// 55.082 us; speedup vs baseline: 2.0063x; 1.3598x over previous
//
#include <hip/hip_runtime.h>
#include <hip/hip_bf16.h>
#include <math.h>

// Problem dims
#define TOK   8192
#define F_DIM 64
#define U_DIM 128
#define N3    384

// Chebyshev expansion: 64 features x 32 coeffs (truncated; err filtered by W)
#define MCH   32
#define KCH   (F_DIM * MCH)      // 2048
#define RCH   6.0f

// GEMM tiling: BK=64 = 2 features/step
#define BM    64
#define BK    64
#define KSPL  4
#define KRANGE (KCH / KSPL)      // 512 (16 features)
#define NST   (KRANGE / BK)      // 8
#define NF    16                 // features per split
#define ASTR  72

typedef _Float16 h16x8 __attribute__((ext_vector_type(8)));
typedef _Float16 h16x4 __attribute__((ext_vector_type(4)));
typedef __bf16   bf16x8 __attribute__((ext_vector_type(8)));
typedef float    f32x4 __attribute__((ext_vector_type(4)));

#define WG_SYNC() do {                                       \
    asm volatile("s_waitcnt lgkmcnt(0)" ::: "memory");       \
    __builtin_amdgcn_s_barrier();                            \
    __builtin_amdgcn_sched_barrier(0);                       \
} while (0)

__device__ __forceinline__ float bflo(unsigned u) { u <<= 16; return __builtin_bit_cast(float, u); }
__device__ __forceinline__ float bfhi(unsigned u) { u &= 0xffff0000u; return __builtin_bit_cast(float, u); }
__device__ __forceinline__ unsigned bfpack(float a, float b) {
    unsigned pa = (unsigned)__builtin_bit_cast(unsigned short, (__bf16)a);
    unsigned pb = (unsigned)__builtin_bit_cast(unsigned short, (__bf16)b);
    return pa | (pb << 16);
}

// ---------------------------------------------------------------------------
// Kernel P1: blocks 0..255: Chebyshev fit (64 nodes, 32 coeffs kept),
// 32 k's per block, LDS-cooperative, exact erf-gelu.
// Blocks 256..267: pack lin_w/sm_w into MFMA B-frag order.
// ---------------------------------------------------------------------------
__global__ __launch_bounds__(256) void vsn_prep18(
    const float* __restrict__ fw,
    const float* __restrict__ fb,
    const float* __restrict__ lin_w,
    const float* __restrict__ sm_w,
    float* __restrict__ c_ws,
    __bf16* __restrict__ linf,
    __bf16* __restrict__ smf)
{
    const int t = threadIdx.x;
    const int bx = blockIdx.x;
    if (bx >= 256) {
        const int xb = bx - 256;
        if (xb < 8) {
#pragma unroll
            for (int i = 0; i < 8; ++i) {
                int idx = xb * 2048 + i * 256 + t;
                int j = idx & 7, l = (idx >> 3) & 63, q = idx >> 9;
                int ks = q >> 3, nj = q & 7;
                int k = ks * 32 + (l >> 4) * 8 + j;
                int n = nj * 16 + (l & 15);
                linf[idx] = (__bf16)lin_w[k * U_DIM + n];
            }
        } else {
            int sb = xb - 8;
#pragma unroll
            for (int i = 0; i < 8; ++i) {
                int idx = sb * 2048 + i * 256 + t;
                int j = idx & 7, l = (idx >> 3) & 63, q = idx >> 9;
                int ks = q >> 2, nj = q & 3;
                int k = ks * 32 + (l >> 4) * 8 + j;
                int n = nj * 16 + (l & 15);
                smf[idx] = (__bf16)sm_w[k * F_DIM + n];
            }
        }
        return;
    }

    __shared__ float ctab[MCH][67];   // [m][i], includes 2/64 and m==0 half
    __shared__ float g_lds[32][67];   // [k][i]
    const int k0 = bx * 32;

#pragma unroll
    for (int r = 0; r < 8; ++r) {
        int idx = r * 256 + t;        // 0..2047 = 32 m x 64 i
        int m = idx >> 6, i = idx & 63;
        float ang = 3.14159265358979f * (float)m * ((float)i + 0.5f) * (1.0f / 64.0f);
        ctab[m][i] = cosf(ang) * (2.0f / 64.0f) * (m == 0 ? 0.5f : 1.0f);
    }
    __syncthreads();

    // g: 32 k x 64 nodes, 8 evals/thread
#pragma unroll
    for (int r = 0; r < 8; ++r) {
        int idx = r * 256 + t;
        int k = idx >> 6, i = idx & 63;
        float xi = ctab[1][i] * (RCH * 32.0f);     // = R*cos(pi(i+.5)/64)
        float z = fmaf(fw[k0 + k], xi, fb[k0 + k]);
        g_lds[k][i] = 0.5f * z * (1.0f + erff(z * 0.70710678f));
    }
    __syncthreads();

    // dots: thread = (k = t>>3, m0 = (t&7)*4), 4 dots of 64
    const int k = t >> 3, m0 = (t & 7) * 4;
    float a[4] = {0.f, 0.f, 0.f, 0.f};
    for (int i = 0; i < 64; ++i) {
        float gval = g_lds[k][i];
#pragma unroll
        for (int mm = 0; mm < 4; ++mm)
            a[mm] = fmaf(gval, ctab[m0 + mm][i], a[mm]);
    }
    float* dst = &c_ws[(size_t)(k0 + k) * MCH + m0];
#pragma unroll
    for (int mm = 0; mm < 4; ++mm) dst[mm] = a[mm];
}

// ---------------------------------------------------------------------------
// Kernel P2: C-build. Cw[f*32+m][n] = sum_j c[f*128+j][m]·W[f*128+j][n],
// f32 accumulate, packed f16 GEMM layout: Cw[(f*384+ng)*32 + m].
// grid (64 f, 3 mat) x 256 thr; thread = (n0=(t&31)*4, mq=t>>5 -> 4 m).
// ---------------------------------------------------------------------------
__global__ __launch_bounds__(256) void vsn_cbuild18(
    const float* __restrict__ c_ws,
    const float* __restrict__ elu_w,
    const float* __restrict__ gate_w,
    const float* __restrict__ proj_w,
    _Float16* __restrict__ Cw)
{
    __shared__ float c_lds[128 * MCH];   // 16 KB  [j][m]
    __shared__ float w_lds[32 * 128];    // 16 KB  [jj][n]
    const int f = blockIdx.x, mat = blockIdx.y;
    const float* W = (mat == 0) ? elu_w : (mat == 1 ? gate_w : proj_w);
    const int t = threadIdx.x;

    {   // stage c_f (4096 floats, coalesced f32x4)
        const f32x4* src = (const f32x4*)&c_ws[(size_t)f * 128 * MCH];
        f32x4* dst = (f32x4*)c_lds;
#pragma unroll
        for (int i = 0; i < 4; ++i) dst[i * 256 + t] = src[i * 256 + t];
    }

    const int n0 = (t & 31) * 4;
    const int mq = t >> 5;               // m = mq*4 + e
    float acc[4][4];
#pragma unroll
    for (int e = 0; e < 4; ++e)
#pragma unroll
        for (int q = 0; q < 4; ++q) acc[e][q] = 0.f;

    for (int jc = 0; jc < 4; ++jc) {
        __syncthreads();
        {
            const f32x4* src = (const f32x4*)&W[(size_t)(f * 128 + jc * 32) * U_DIM];
            f32x4* dst = (f32x4*)w_lds;
#pragma unroll
            for (int r = 0; r < 4; ++r) dst[r * 256 + t] = src[r * 256 + t];
        }
        __syncthreads();

#pragma unroll 4
        for (int jj = 0; jj < 32; ++jj) {
            const int j = jc * 32 + jj;
            f32x4 wv = *(const f32x4*)&w_lds[jj * 128 + n0];
            f32x4 cv = *(const f32x4*)&c_lds[j * MCH + mq * 4];
#pragma unroll
            for (int e = 0; e < 4; ++e)
#pragma unroll
                for (int q = 0; q < 4; ++q)
                    acc[e][q] = fmaf(cv[e], wv[q], acc[e][q]);
        }
    }

#pragma unroll
    for (int q = 0; q < 4; ++q) {
        const int ng = mat * U_DIM + n0 + q;
        h16x4 v;
#pragma unroll
        for (int e = 0; e < 4; ++e) v[e] = (_Float16)acc[e][q];
        *(h16x4*)&Cw[(((size_t)f * N3) + ng) * 32 + mq * 4] = v;
    }
}

// ---------------------------------------------------------------------------
// Kernel 3: Chebyshev GEMM, K=2048, NST=8 (2 features/step).
// grid (KSPL=4, TOK/64=128), 256 thr (4 waves n-split 96, acc[4][6]),
// f16 MFMA, ping-pong B. XCD id%8 in {s,s+4}: Cw slice (393KB) L2-resident.
// ---------------------------------------------------------------------------
__global__ __launch_bounds__(256, 2) void vsn_gemm18(
    const float* __restrict__ x,
    const _Float16* __restrict__ Cw,
    __bf16* __restrict__ Hp)
{
    __shared__ float     x_lds[BM][NF + 1];
    __shared__ _Float16  a_lds[2][BM][ASTR];

    const int t    = threadIdx.x;
    const int wave = t >> 6;
    const int lane = t & 63;
    const int s     = blockIdx.x;
    const int tok0  = blockIdx.y * BM;
    const int kbase = s * KRANGE;
    const int nbase = wave * 96;
    const int lr  = lane & 15;
    const int lk8 = (lane >> 4) * 8;

    // stage x (64 tok x 16 features of this split); feature = k>>5
#pragma unroll
    for (int i = 0; i < (BM * NF) / 256; ++i) {
        int idx = i * 256 + t;
        int r = idx >> 4, c = idx & 15;
        x_lds[r][c] = x[(size_t)(tok0 + r) * F_DIM + (kbase >> 5) + c];
    }

    f32x4 acc[4][6];
#pragma unroll
    for (int i = 0; i < 4; ++i)
#pragma unroll
        for (int j = 0; j < 6; ++j)
            acc[i][j] = (f32x4){0.f, 0.f, 0.f, 0.f};

    const int m_a = t >> 2;          // 0..63: token row
    const int q   = t & 3;           // strip: feature q>>1, m0 = (q&1)*16
    const int kk  = q * 16;

    // A-tile: T_m(x~), m in [(q&1)*16, +16), feature = st*2 + (q>>1)
    auto cheb_write = [&](int st, int buf) {
        float xr = x_lds[m_a][st * 2 + (q >> 1)];
        float xt = fminf(fmaxf(xr * (1.0f / RCH), -1.0f), 1.0f);
        float x2 = xt + xt;
        float s1 = sqrtf(fmaxf(fmaf(-xt, xt, 1.0f), 0.0f));
        float T2 = fmaf(x2, xt, -1.0f),      S2 = x2 * s1;
        float T4 = fmaf(T2 + T2, T2, -1.0f), S4 = (T2 + T2) * S2;
        float T8 = fmaf(T4 + T4, T4, -1.0f), S8 = (T4 + T4) * S4;
        float T16 = fmaf(T8 + T8, T8, -1.0f), S16 = (T8 + T8) * S8;
        float Ta = (q & 1) ? T16 : 1.0f;
        float Sa = (q & 1) ? S16 : 0.0f;
        float v0 = Ta;
        float v1 = fmaf(xt, Ta, -Sa * s1);   // T_{m0+1}
        h16x8 o0, o1;
        o0[0] = (_Float16)v0; o0[1] = (_Float16)v1;
#pragma unroll
        for (int i = 2; i < 8; ++i) {
            float v = fmaf(x2, v1, -v0); v0 = v1; v1 = v;
            o0[i] = (_Float16)v;
        }
#pragma unroll
        for (int i = 0; i < 8; ++i) {
            float v = fmaf(x2, v1, -v0); v0 = v1; v1 = v;
            o1[i] = (_Float16)v;
        }
        *(h16x8*)&a_lds[buf][m_a][kk]     = o0;
        *(h16x8*)&a_lds[buf][m_a][kk + 8] = o1;
    };

    const _Float16* bb = Cw + (size_t)(kbase >> 5) * (N3 * 32)
                            + (nbase + lr) * 32 + lk8;
    auto loadB = [&](int st, int ksi, h16x8 (&dst)[6]) {
        const _Float16* p = bb + (size_t)(st * 2 + ksi) * (N3 * 32);
#pragma unroll
        for (int j = 0; j < 6; ++j)
            dst[j] = *(const h16x8*)(p + j * 512);
    };

    h16x8 bX[6], bY[6];

    WG_SYNC();                     // x staged
    cheb_write(0, 0);
    loadB(0, 0, bX);

    for (int st = 0; st < NST - 1; ++st) {
        const int cur = st & 1;
        WG_SYNC();                 // a_lds[cur] ready; buf cur^1 free
        loadB(st, 1, bY);
        cheb_write(st + 1, cur ^ 1);

        h16x8 af[4];
#pragma unroll
        for (int i = 0; i < 4; ++i)
            af[i] = *(const h16x8*)&a_lds[cur][i * 16 + lr][lk8];
#pragma unroll
        for (int i = 0; i < 4; ++i)
#pragma unroll
            for (int j = 0; j < 6; ++j)
                acc[i][j] = __builtin_amdgcn_mfma_f32_16x16x32_f16(
                    af[i], bX[j], acc[i][j], 0, 0, 0);

        loadB(st + 1, 0, bX);
#pragma unroll
        for (int i = 0; i < 4; ++i)
            af[i] = *(const h16x8*)&a_lds[cur][i * 16 + lr][32 + lk8];
#pragma unroll
        for (int i = 0; i < 4; ++i)
#pragma unroll
            for (int j = 0; j < 6; ++j)
                acc[i][j] = __builtin_amdgcn_mfma_f32_16x16x32_f16(
                    af[i], bY[j], acc[i][j], 0, 0, 0);
    }
    {
        const int cur = (NST - 1) & 1;
        WG_SYNC();
        loadB(NST - 1, 1, bY);
        h16x8 af[4];
#pragma unroll
        for (int i = 0; i < 4; ++i)
            af[i] = *(const h16x8*)&a_lds[cur][i * 16 + lr][lk8];
#pragma unroll
        for (int i = 0; i < 4; ++i)
#pragma unroll
            for (int j = 0; j < 6; ++j)
                acc[i][j] = __builtin_amdgcn_mfma_f32_16x16x32_f16(
                    af[i], bX[j], acc[i][j], 0, 0, 0);
#pragma unroll
        for (int i = 0; i < 4; ++i)
            af[i] = *(const h16x8*)&a_lds[cur][i * 16 + lr][32 + lk8];
#pragma unroll
        for (int i = 0; i < 4; ++i)
#pragma unroll
            for (int j = 0; j < 6; ++j)
                acc[i][j] = __builtin_amdgcn_mfma_f32_16x16x32_f16(
                    af[i], bY[j], acc[i][j], 0, 0, 0);
    }

    __bf16* Hs = Hp + (size_t)s * ((size_t)TOK * N3);
    const int r0 = (lane >> 4) * 4;
#pragma unroll
    for (int i = 0; i < 4; ++i)
#pragma unroll
        for (int j = 0; j < 6; ++j)
#pragma unroll
            for (int r = 0; r < 4; ++r)
                Hs[(size_t)(tok0 + i * 16 + r0 + r) * N3 + nbase + j * 16 + lr]
                    = (__bf16)acc[i][j][r];
}

// ---------------------------------------------------------------------------
// Kernel 4: MFMA epilogue (R17-validated, unchanged). 256 WGs x 128 thr.
// ---------------------------------------------------------------------------
__global__ __launch_bounds__(128) void vsn_epi18(
    const float* __restrict__ x,
    const __bf16* __restrict__ Hp,
    const __bf16* __restrict__ linf,
    const __bf16* __restrict__ smf,
    const float* __restrict__ elu_b,
    const float* __restrict__ lin_b,
    const float* __restrict__ gate_b,
    const float* __restrict__ ln_g,
    const float* __restrict__ ln_b,
    const float* __restrict__ sm_b,
    float* __restrict__ out)
{
    __shared__ __bf16 linf_lds[32 * 512];
    __shared__ __bf16 smf_lds[16 * 512];
    __shared__ __bf16 h1_lds[2][16][136];
    __shared__ float  g_lds[2][16][132];
    __shared__ float  p_lds[2][16][132];

    const int t = threadIdx.x, w = t >> 6, lane = t & 63;
    const int tokb = blockIdx.x * 32 + w * 16;

    {
        const uint4* s4 = (const uint4*)linf;
        uint4* d4 = (uint4*)linf_lds;
#pragma unroll
        for (int i = 0; i < 16; ++i) d4[i * 128 + t] = s4[i * 128 + t];
        const uint4* s2 = (const uint4*)smf;
        uint4* d2 = (uint4*)smf_lds;
#pragma unroll
        for (int i = 0; i < 8; ++i) d2[i * 128 + t] = s2[i * 128 + t];
    }

    const float2 eb = *(const float2*)&elu_b[2 * lane];
    const float2 gb = *(const float2*)&gate_b[2 * lane];
#pragma unroll 4
    for (int tk = 0; tk < 16; ++tk) {
        const unsigned short* base =
            (const unsigned short*)Hp + (size_t)(tokb + tk) * N3;
        float a0 = 0.f, a1 = 0.f, g0 = 0.f, g1 = 0.f, p0 = 0.f, p1 = 0.f;
#pragma unroll
        for (int s = 0; s < KSPL; ++s) {
            const unsigned short* bs = base + (size_t)s * TOK * N3;
            unsigned ua = *(const unsigned*)(bs + 2 * lane);
            unsigned ug = *(const unsigned*)(bs + 128 + 2 * lane);
            unsigned up = *(const unsigned*)(bs + 256 + 2 * lane);
            a0 += bflo(ua); a1 += bfhi(ua);
            g0 += bflo(ug); g1 += bfhi(ug);
            p0 += bflo(up); p1 += bfhi(up);
        }
        float e0 = a0 + eb.x, e1 = a1 + eb.y;
        float h10 = (e0 > 0.f) ? e0 : expm1f(e0);
        float h11 = (e1 > 0.f) ? e1 : expm1f(e1);
        *(unsigned*)((char*)&h1_lds[w][tk][0] + 4 * lane) = bfpack(h10, h11);
        g_lds[w][tk][2 * lane]     = 1.f / (1.f + __expf(-(g0 + gb.x)));
        g_lds[w][tk][2 * lane + 1] = 1.f / (1.f + __expf(-(g1 + gb.y)));
        p_lds[w][tk][2 * lane]     = p0;
        p_lds[w][tk][2 * lane + 1] = p1;
    }
    __syncthreads();

    const int c0 = lane & 15;
    const int rg = lane >> 4;

    f32x4 acc[8];
#pragma unroll
    for (int nj = 0; nj < 8; ++nj) acc[nj] = (f32x4){0.f, 0.f, 0.f, 0.f};
#pragma unroll
    for (int ks = 0; ks < 4; ++ks) {
        bf16x8 af = *(const bf16x8*)&h1_lds[w][c0][ks * 32 + rg * 8];
#pragma unroll
        for (int nj = 0; nj < 8; ++nj) {
            bf16x8 bf = *(const bf16x8*)&linf_lds[((ks * 8 + nj) * 64 + lane) * 8];
            acc[nj] = __builtin_amdgcn_mfma_f32_16x16x32_bf16(af, bf, acc[nj], 0, 0, 0);
        }
    }

    float h[8][4];
#pragma unroll
    for (int nj = 0; nj < 8; ++nj) {
        float lb = lin_b[c0 + 16 * nj];
#pragma unroll
        for (int r = 0; r < 4; ++r) {
            int tokr = rg * 4 + r;
            float h2 = acc[nj][r] + lb;
            float g  = g_lds[w][tokr][c0 + 16 * nj];
            float p  = p_lds[w][tokr][c0 + 16 * nj];
            h[nj][r] = fmaf(g, h2, p);
        }
    }

    float mu[4], rstd[4];
#pragma unroll
    for (int r = 0; r < 4; ++r) {
        float s = 0.f;
#pragma unroll
        for (int nj = 0; nj < 8; ++nj) s += h[nj][r];
        s += __shfl_xor(s, 1); s += __shfl_xor(s, 2);
        s += __shfl_xor(s, 4); s += __shfl_xor(s, 8);
        mu[r] = s * (1.0f / 128.0f);
        float v = 0.f;
#pragma unroll
        for (int nj = 0; nj < 8; ++nj) {
            float d = h[nj][r] - mu[r];
            v = fmaf(d, d, v);
        }
        v += __shfl_xor(v, 1); v += __shfl_xor(v, 2);
        v += __shfl_xor(v, 4); v += __shfl_xor(v, 8);
        rstd[r] = rsqrtf(v * (1.0f / 128.0f) + 1e-3f);
    }

#pragma unroll
    for (int nj = 0; nj < 8; ++nj) {
        int col = c0 + 16 * nj;
        float lg = ln_g[col], lb = ln_b[col];
#pragma unroll
        for (int r = 0; r < 4; ++r) {
            float y = fmaf((h[nj][r] - mu[r]) * rstd[r], lg, lb);
            h1_lds[w][rg * 4 + r][col] = (__bf16)y;
        }
    }

    f32x4 acc2[4];
#pragma unroll
    for (int nj = 0; nj < 4; ++nj) acc2[nj] = (f32x4){0.f, 0.f, 0.f, 0.f};
#pragma unroll
    for (int ks = 0; ks < 4; ++ks) {
        bf16x8 af = *(const bf16x8*)&h1_lds[w][c0][ks * 32 + rg * 8];
#pragma unroll
        for (int nj = 0; nj < 4; ++nj) {
            bf16x8 bf = *(const bf16x8*)&smf_lds[((ks * 4 + nj) * 64 + lane) * 8];
            acc2[nj] = __builtin_amdgcn_mfma_f32_16x16x32_bf16(af, bf, acc2[nj], 0, 0, 0);
        }
    }

    float lgt[4][4];
#pragma unroll
    for (int nj = 0; nj < 4; ++nj) {
        float sb = sm_b[c0 + 16 * nj];
#pragma unroll
        for (int r = 0; r < 4; ++r) lgt[nj][r] = acc2[nj][r] + sb;
    }
#pragma unroll
    for (int r = 0; r < 4; ++r) {
        float mx = fmaxf(fmaxf(lgt[0][r], lgt[1][r]), fmaxf(lgt[2][r], lgt[3][r]));
        mx = fmaxf(mx, __shfl_xor(mx, 1)); mx = fmaxf(mx, __shfl_xor(mx, 2));
        mx = fmaxf(mx, __shfl_xor(mx, 4)); mx = fmaxf(mx, __shfl_xor(mx, 8));
        float ex[4], se = 0.f;
#pragma unroll
        for (int nj = 0; nj < 4; ++nj) {
            ex[nj] = __expf(lgt[nj][r] - mx);
            se += ex[nj];
        }
        se += __shfl_xor(se, 1); se += __shfl_xor(se, 2);
        se += __shfl_xor(se, 4); se += __shfl_xor(se, 8);
        float inv = 1.0f / se;
        int tok = tokb + rg * 4 + r;
#pragma unroll
        for (int nj = 0; nj < 4; ++nj) {
            int f = c0 + 16 * nj;
            float wgt = ex[nj] * inv;
            float xv = x[(size_t)tok * F_DIM + f];
            out[(size_t)tok * F_DIM + f] = xv * wgt;
            out[(size_t)TOK * F_DIM + (size_t)tok * F_DIM + f] = wgt;
        }
    }
}

// ---------------------------------------------------------------------------
extern "C" void kernel_launch(void* const* d_in, const int* in_sizes, int n_in,
                              void* d_out, int out_size, void* d_ws, size_t ws_size,
                              hipStream_t stream)
{
    const float* x      = (const float*)d_in[0];
    const float* fw     = (const float*)d_in[1];
    const float* fb     = (const float*)d_in[2];
    const float* elu_w  = (const float*)d_in[3];
    const float* elu_b  = (const float*)d_in[4];
    const float* lin_w  = (const float*)d_in[5];
    const float* lin_b  = (const float*)d_in[6];
    const float* gate_w = (const float*)d_in[7];
    const float* gate_b = (const float*)d_in[8];
    const float* proj_w = (const float*)d_in[9];
    const float* ln_g   = (const float*)d_in[10];
    const float* ln_b   = (const float*)d_in[11];
    const float* sm_w   = (const float*)d_in[12];
    const float* sm_b   = (const float*)d_in[13];

    // ws: Cw 1.57MB | Hp 25.17MB | linf 32KB | smf 16KB | c_ws 1MB
    char* wsb = (char*)d_ws;
    _Float16* Cw   = (_Float16*)wsb;
    __bf16*   Hp   = (__bf16*)(wsb + (size_t)KCH * N3 * 2);
    __bf16*   linf = (__bf16*)(wsb + (size_t)KCH * N3 * 2
                                   + (size_t)KSPL * TOK * N3 * 2);
    __bf16*   smf  = linf + U_DIM * U_DIM;
    float*    c_ws = (float*)((char*)smf + U_DIM * F_DIM * 2);

    vsn_prep18<<<268, 256, 0, stream>>>(fw, fb, lin_w, sm_w, c_ws, linf, smf);
    vsn_cbuild18<<<dim3(64, 3), 256, 0, stream>>>(c_ws, elu_w, gate_w, proj_w, Cw);
    vsn_gemm18<<<dim3(KSPL, TOK / BM), 256, 0, stream>>>(x, Cw, Hp);
    vsn_epi18<<<TOK / 32, 128, 0, stream>>>(x, Hp, linf, smf, elu_b, lin_b,
                                            gate_b, ln_g, ln_b, sm_b,
                                            (float*)d_out);
}

// Round 20
// 54.888 us; speedup vs baseline: 2.0134x; 1.0035x over previous
//
#include <hip/hip_runtime.h>
#include <hip/hip_bf16.h>
#include <math.h>

// Problem dims
#define TOK   8192
#define F_DIM 64
#define U_DIM 128
#define N3    384

// Chebyshev expansion: 64 features x 32 coeffs (truncated; err filtered by W)
// [R19 probe: MCH=16 -> absmax 0.037 FAIL; MCH=32 -> 0.0039 == bf16 noise floor]
#define MCH   32
#define KCH   (F_DIM * MCH)      // 2048
#define RCH   6.0f

// GEMM tiling: BK=64 = 2 features/step
#define BM    64
#define BK    64
#define KSPL  4
#define KRANGE (KCH / KSPL)      // 512 (16 features)
#define NST   (KRANGE / BK)      // 8
#define NF    16                 // features per split
#define ASTR  72

typedef _Float16 h16x8 __attribute__((ext_vector_type(8)));
typedef _Float16 h16x4 __attribute__((ext_vector_type(4)));
typedef __bf16   bf16x8 __attribute__((ext_vector_type(8)));
typedef float    f32x4 __attribute__((ext_vector_type(4)));

#define WG_SYNC() do {                                       \
    asm volatile("s_waitcnt lgkmcnt(0)" ::: "memory");       \
    __builtin_amdgcn_s_barrier();                            \
    __builtin_amdgcn_sched_barrier(0);                       \
} while (0)

__device__ __forceinline__ float bflo(unsigned u) { u <<= 16; return __builtin_bit_cast(float, u); }
__device__ __forceinline__ float bfhi(unsigned u) { u &= 0xffff0000u; return __builtin_bit_cast(float, u); }
__device__ __forceinline__ unsigned bfpack(float a, float b) {
    unsigned pa = (unsigned)__builtin_bit_cast(unsigned short, (__bf16)a);
    unsigned pb = (unsigned)__builtin_bit_cast(unsigned short, (__bf16)b);
    return pa | (pb << 16);
}

// ---------------------------------------------------------------------------
// Kernel P1: blocks 0..255: Chebyshev fit (64 nodes, 32 coeffs kept),
// 32 k's per block, LDS-cooperative, exact erf-gelu.
// Blocks 256..267: pack lin_w/sm_w into MFMA B-frag order.
// ---------------------------------------------------------------------------
__global__ __launch_bounds__(256) void vsn_prep20(
    const float* __restrict__ fw,
    const float* __restrict__ fb,
    const float* __restrict__ lin_w,
    const float* __restrict__ sm_w,
    float* __restrict__ c_ws,
    __bf16* __restrict__ linf,
    __bf16* __restrict__ smf)
{
    const int t = threadIdx.x;
    const int bx = blockIdx.x;
    if (bx >= 256) {
        const int xb = bx - 256;
        if (xb < 8) {
#pragma unroll
            for (int i = 0; i < 8; ++i) {
                int idx = xb * 2048 + i * 256 + t;
                int j = idx & 7, l = (idx >> 3) & 63, q = idx >> 9;
                int ks = q >> 3, nj = q & 7;
                int k = ks * 32 + (l >> 4) * 8 + j;
                int n = nj * 16 + (l & 15);
                linf[idx] = (__bf16)lin_w[k * U_DIM + n];
            }
        } else {
            int sb = xb - 8;
#pragma unroll
            for (int i = 0; i < 8; ++i) {
                int idx = sb * 2048 + i * 256 + t;
                int j = idx & 7, l = (idx >> 3) & 63, q = idx >> 9;
                int ks = q >> 2, nj = q & 3;
                int k = ks * 32 + (l >> 4) * 8 + j;
                int n = nj * 16 + (l & 15);
                smf[idx] = (__bf16)sm_w[k * F_DIM + n];
            }
        }
        return;
    }

    __shared__ float ctab[MCH][67];   // [m][i], includes 2/64 and m==0 half
    __shared__ float g_lds[32][67];   // [k][i]
    const int k0 = bx * 32;

#pragma unroll
    for (int r = 0; r < 8; ++r) {
        int idx = r * 256 + t;        // 0..2047 = 32 m x 64 i
        int m = idx >> 6, i = idx & 63;
        float ang = 3.14159265358979f * (float)m * ((float)i + 0.5f) * (1.0f / 64.0f);
        ctab[m][i] = cosf(ang) * (2.0f / 64.0f) * (m == 0 ? 0.5f : 1.0f);
    }
    __syncthreads();

    // g: 32 k x 64 nodes, 8 evals/thread
#pragma unroll
    for (int r = 0; r < 8; ++r) {
        int idx = r * 256 + t;
        int k = idx >> 6, i = idx & 63;
        float xi = ctab[1][i] * (RCH * 32.0f);     // = R*cos(pi(i+.5)/64)
        float z = fmaf(fw[k0 + k], xi, fb[k0 + k]);
        g_lds[k][i] = 0.5f * z * (1.0f + erff(z * 0.70710678f));
    }
    __syncthreads();

    // dots: thread = (k = t>>3, m0 = (t&7)*4), 4 dots of 64
    const int k = t >> 3, m0 = (t & 7) * 4;
    float a[4] = {0.f, 0.f, 0.f, 0.f};
    for (int i = 0; i < 64; ++i) {
        float gval = g_lds[k][i];
#pragma unroll
        for (int mm = 0; mm < 4; ++mm)
            a[mm] = fmaf(gval, ctab[m0 + mm][i], a[mm]);
    }
    float* dst = &c_ws[(size_t)(k0 + k) * MCH + m0];
#pragma unroll
    for (int mm = 0; mm < 4; ++mm) dst[mm] = a[mm];
}

// ---------------------------------------------------------------------------
// Kernel P2: C-build. Cw[f*32+m][n] = sum_j c[f*128+j][m]·W[f*128+j][n],
// f32 accumulate, packed f16 GEMM layout: Cw[(f*384+ng)*32 + m].
// grid (64 f, 3 mat) x 256 thr; thread = (n0=(t&31)*4, mq=t>>5 -> 4 m).
// ---------------------------------------------------------------------------
__global__ __launch_bounds__(256) void vsn_cbuild20(
    const float* __restrict__ c_ws,
    const float* __restrict__ elu_w,
    const float* __restrict__ gate_w,
    const float* __restrict__ proj_w,
    _Float16* __restrict__ Cw)
{
    __shared__ float c_lds[128 * MCH];   // 16 KB  [j][m]
    __shared__ float w_lds[32 * 128];    // 16 KB  [jj][n]
    const int f = blockIdx.x, mat = blockIdx.y;
    const float* W = (mat == 0) ? elu_w : (mat == 1 ? gate_w : proj_w);
    const int t = threadIdx.x;

    {   // stage c_f (4096 floats, coalesced f32x4)
        const f32x4* src = (const f32x4*)&c_ws[(size_t)f * 128 * MCH];
        f32x4* dst = (f32x4*)c_lds;
#pragma unroll
        for (int i = 0; i < 4; ++i) dst[i * 256 + t] = src[i * 256 + t];
    }

    const int n0 = (t & 31) * 4;
    const int mq = t >> 5;               // m = mq*4 + e
    float acc[4][4];
#pragma unroll
    for (int e = 0; e < 4; ++e)
#pragma unroll
        for (int q = 0; q < 4; ++q) acc[e][q] = 0.f;

    for (int jc = 0; jc < 4; ++jc) {
        __syncthreads();
        {
            const f32x4* src = (const f32x4*)&W[(size_t)(f * 128 + jc * 32) * U_DIM];
            f32x4* dst = (f32x4*)w_lds;
#pragma unroll
            for (int r = 0; r < 4; ++r) dst[r * 256 + t] = src[r * 256 + t];
        }
        __syncthreads();

#pragma unroll 4
        for (int jj = 0; jj < 32; ++jj) {
            const int j = jc * 32 + jj;
            f32x4 wv = *(const f32x4*)&w_lds[jj * 128 + n0];
            f32x4 cv = *(const f32x4*)&c_lds[j * MCH + mq * 4];
#pragma unroll
            for (int e = 0; e < 4; ++e)
#pragma unroll
                for (int q = 0; q < 4; ++q)
                    acc[e][q] = fmaf(cv[e], wv[q], acc[e][q]);
        }
    }

#pragma unroll
    for (int q = 0; q < 4; ++q) {
        const int ng = mat * U_DIM + n0 + q;
        h16x4 v;
#pragma unroll
        for (int e = 0; e < 4; ++e) v[e] = (_Float16)acc[e][q];
        *(h16x4*)&Cw[(((size_t)f * N3) + ng) * 32 + mq * 4] = v;
    }
}

// ---------------------------------------------------------------------------
// Kernel 3: Chebyshev GEMM, K=2048, NST=8 (2 features/step).
// grid (KSPL=4, TOK/64=128), 256 thr (4 waves n-split 96, acc[4][6]),
// f16 MFMA, ping-pong B. XCD id%8 in {s,s+4}: Cw slice (393KB) L2-resident.
// ---------------------------------------------------------------------------
__global__ __launch_bounds__(256, 2) void vsn_gemm20(
    const float* __restrict__ x,
    const _Float16* __restrict__ Cw,
    __bf16* __restrict__ Hp)
{
    __shared__ float     x_lds[BM][NF + 1];
    __shared__ _Float16  a_lds[2][BM][ASTR];

    const int t    = threadIdx.x;
    const int wave = t >> 6;
    const int lane = t & 63;
    const int s     = blockIdx.x;
    const int tok0  = blockIdx.y * BM;
    const int kbase = s * KRANGE;
    const int nbase = wave * 96;
    const int lr  = lane & 15;
    const int lk8 = (lane >> 4) * 8;

    // stage x (64 tok x 16 features of this split); feature = k>>5
#pragma unroll
    for (int i = 0; i < (BM * NF) / 256; ++i) {
        int idx = i * 256 + t;
        int r = idx >> 4, c = idx & 15;
        x_lds[r][c] = x[(size_t)(tok0 + r) * F_DIM + (kbase >> 5) + c];
    }

    f32x4 acc[4][6];
#pragma unroll
    for (int i = 0; i < 4; ++i)
#pragma unroll
        for (int j = 0; j < 6; ++j)
            acc[i][j] = (f32x4){0.f, 0.f, 0.f, 0.f};

    const int m_a = t >> 2;          // 0..63: token row
    const int q   = t & 3;           // strip: feature q>>1, m0 = (q&1)*16
    const int kk  = q * 16;

    // A-tile: T_m(x~), m in [(q&1)*16, +16), feature = st*2 + (q>>1)
    auto cheb_write = [&](int st, int buf) {
        float xr = x_lds[m_a][st * 2 + (q >> 1)];
        float xt = fminf(fmaxf(xr * (1.0f / RCH), -1.0f), 1.0f);
        float x2 = xt + xt;
        float s1 = sqrtf(fmaxf(fmaf(-xt, xt, 1.0f), 0.0f));
        float T2 = fmaf(x2, xt, -1.0f),      S2 = x2 * s1;
        float T4 = fmaf(T2 + T2, T2, -1.0f), S4 = (T2 + T2) * S2;
        float T8 = fmaf(T4 + T4, T4, -1.0f), S8 = (T4 + T4) * S4;
        float T16 = fmaf(T8 + T8, T8, -1.0f), S16 = (T8 + T8) * S8;
        float Ta = (q & 1) ? T16 : 1.0f;
        float Sa = (q & 1) ? S16 : 0.0f;
        float v0 = Ta;
        float v1 = fmaf(xt, Ta, -Sa * s1);   // T_{m0+1}
        h16x8 o0, o1;
        o0[0] = (_Float16)v0; o0[1] = (_Float16)v1;
#pragma unroll
        for (int i = 2; i < 8; ++i) {
            float v = fmaf(x2, v1, -v0); v0 = v1; v1 = v;
            o0[i] = (_Float16)v;
        }
#pragma unroll
        for (int i = 0; i < 8; ++i) {
            float v = fmaf(x2, v1, -v0); v0 = v1; v1 = v;
            o1[i] = (_Float16)v;
        }
        *(h16x8*)&a_lds[buf][m_a][kk]     = o0;
        *(h16x8*)&a_lds[buf][m_a][kk + 8] = o1;
    };

    const _Float16* bb = Cw + (size_t)(kbase >> 5) * (N3 * 32)
                            + (nbase + lr) * 32 + lk8;
    auto loadB = [&](int st, int ksi, h16x8 (&dst)[6]) {
        const _Float16* p = bb + (size_t)(st * 2 + ksi) * (N3 * 32);
#pragma unroll
        for (int j = 0; j < 6; ++j)
            dst[j] = *(const h16x8*)(p + j * 512);
    };

    h16x8 bX[6], bY[6];

    WG_SYNC();                     // x staged
    cheb_write(0, 0);
    loadB(0, 0, bX);

    for (int st = 0; st < NST - 1; ++st) {
        const int cur = st & 1;
        WG_SYNC();                 // a_lds[cur] ready; buf cur^1 free
        loadB(st, 1, bY);
        cheb_write(st + 1, cur ^ 1);

        h16x8 af[4];
#pragma unroll
        for (int i = 0; i < 4; ++i)
            af[i] = *(const h16x8*)&a_lds[cur][i * 16 + lr][lk8];
#pragma unroll
        for (int i = 0; i < 4; ++i)
#pragma unroll
            for (int j = 0; j < 6; ++j)
                acc[i][j] = __builtin_amdgcn_mfma_f32_16x16x32_f16(
                    af[i], bX[j], acc[i][j], 0, 0, 0);

        loadB(st + 1, 0, bX);
#pragma unroll
        for (int i = 0; i < 4; ++i)
            af[i] = *(const h16x8*)&a_lds[cur][i * 16 + lr][32 + lk8];
#pragma unroll
        for (int i = 0; i < 4; ++i)
#pragma unroll
            for (int j = 0; j < 6; ++j)
                acc[i][j] = __builtin_amdgcn_mfma_f32_16x16x32_f16(
                    af[i], bY[j], acc[i][j], 0, 0, 0);
    }
    {
        const int cur = (NST - 1) & 1;
        WG_SYNC();
        loadB(NST - 1, 1, bY);
        h16x8 af[4];
#pragma unroll
        for (int i = 0; i < 4; ++i)
            af[i] = *(const h16x8*)&a_lds[cur][i * 16 + lr][lk8];
#pragma unroll
        for (int i = 0; i < 4; ++i)
#pragma unroll
            for (int j = 0; j < 6; ++j)
                acc[i][j] = __builtin_amdgcn_mfma_f32_16x16x32_f16(
                    af[i], bX[j], acc[i][j], 0, 0, 0);
#pragma unroll
        for (int i = 0; i < 4; ++i)
            af[i] = *(const h16x8*)&a_lds[cur][i * 16 + lr][32 + lk8];
#pragma unroll
        for (int i = 0; i < 4; ++i)
#pragma unroll
            for (int j = 0; j < 6; ++j)
                acc[i][j] = __builtin_amdgcn_mfma_f32_16x16x32_f16(
                    af[i], bY[j], acc[i][j], 0, 0, 0);
    }

    __bf16* Hs = Hp + (size_t)s * ((size_t)TOK * N3);
    const int r0 = (lane >> 4) * 4;
#pragma unroll
    for (int i = 0; i < 4; ++i)
#pragma unroll
        for (int j = 0; j < 6; ++j)
#pragma unroll
            for (int r = 0; r < 4; ++r)
                Hs[(size_t)(tok0 + i * 16 + r0 + r) * N3 + nbase + j * 16 + lr]
                    = (__bf16)acc[i][j][r];
}

// ---------------------------------------------------------------------------
// Kernel 4: MFMA epilogue (validated). 256 WGs x 128 thr; 16 tok/wave.
// ---------------------------------------------------------------------------
__global__ __launch_bounds__(128) void vsn_epi20(
    const float* __restrict__ x,
    const __bf16* __restrict__ Hp,
    const __bf16* __restrict__ linf,
    const __bf16* __restrict__ smf,
    const float* __restrict__ elu_b,
    const float* __restrict__ lin_b,
    const float* __restrict__ gate_b,
    const float* __restrict__ ln_g,
    const float* __restrict__ ln_b,
    const float* __restrict__ sm_b,
    float* __restrict__ out)
{
    __shared__ __bf16 linf_lds[32 * 512];
    __shared__ __bf16 smf_lds[16 * 512];
    __shared__ __bf16 h1_lds[2][16][136];
    __shared__ float  g_lds[2][16][132];
    __shared__ float  p_lds[2][16][132];

    const int t = threadIdx.x, w = t >> 6, lane = t & 63;
    const int tokb = blockIdx.x * 32 + w * 16;

    {
        const uint4* s4 = (const uint4*)linf;
        uint4* d4 = (uint4*)linf_lds;
#pragma unroll
        for (int i = 0; i < 16; ++i) d4[i * 128 + t] = s4[i * 128 + t];
        const uint4* s2 = (const uint4*)smf;
        uint4* d2 = (uint4*)smf_lds;
#pragma unroll
        for (int i = 0; i < 8; ++i) d2[i * 128 + t] = s2[i * 128 + t];
    }

    const float2 eb = *(const float2*)&elu_b[2 * lane];
    const float2 gb = *(const float2*)&gate_b[2 * lane];
#pragma unroll 4
    for (int tk = 0; tk < 16; ++tk) {
        const unsigned short* base =
            (const unsigned short*)Hp + (size_t)(tokb + tk) * N3;
        float a0 = 0.f, a1 = 0.f, g0 = 0.f, g1 = 0.f, p0 = 0.f, p1 = 0.f;
#pragma unroll
        for (int s = 0; s < KSPL; ++s) {
            const unsigned short* bs = base + (size_t)s * TOK * N3;
            unsigned ua = *(const unsigned*)(bs + 2 * lane);
            unsigned ug = *(const unsigned*)(bs + 128 + 2 * lane);
            unsigned up = *(const unsigned*)(bs + 256 + 2 * lane);
            a0 += bflo(ua); a1 += bfhi(ua);
            g0 += bflo(ug); g1 += bfhi(ug);
            p0 += bflo(up); p1 += bfhi(up);
        }
        float e0 = a0 + eb.x, e1 = a1 + eb.y;
        float h10 = (e0 > 0.f) ? e0 : expm1f(e0);
        float h11 = (e1 > 0.f) ? e1 : expm1f(e1);
        *(unsigned*)((char*)&h1_lds[w][tk][0] + 4 * lane) = bfpack(h10, h11);
        g_lds[w][tk][2 * lane]     = 1.f / (1.f + __expf(-(g0 + gb.x)));
        g_lds[w][tk][2 * lane + 1] = 1.f / (1.f + __expf(-(g1 + gb.y)));
        p_lds[w][tk][2 * lane]     = p0;
        p_lds[w][tk][2 * lane + 1] = p1;
    }
    __syncthreads();

    const int c0 = lane & 15;
    const int rg = lane >> 4;

    f32x4 acc[8];
#pragma unroll
    for (int nj = 0; nj < 8; ++nj) acc[nj] = (f32x4){0.f, 0.f, 0.f, 0.f};
#pragma unroll
    for (int ks = 0; ks < 4; ++ks) {
        bf16x8 af = *(const bf16x8*)&h1_lds[w][c0][ks * 32 + rg * 8];
#pragma unroll
        for (int nj = 0; nj < 8; ++nj) {
            bf16x8 bf = *(const bf16x8*)&linf_lds[((ks * 8 + nj) * 64 + lane) * 8];
            acc[nj] = __builtin_amdgcn_mfma_f32_16x16x32_bf16(af, bf, acc[nj], 0, 0, 0);
        }
    }

    float h[8][4];
#pragma unroll
    for (int nj = 0; nj < 8; ++nj) {
        float lb = lin_b[c0 + 16 * nj];
#pragma unroll
        for (int r = 0; r < 4; ++r) {
            int tokr = rg * 4 + r;
            float h2 = acc[nj][r] + lb;
            float g  = g_lds[w][tokr][c0 + 16 * nj];
            float p  = p_lds[w][tokr][c0 + 16 * nj];
            h[nj][r] = fmaf(g, h2, p);
        }
    }

    float mu[4], rstd[4];
#pragma unroll
    for (int r = 0; r < 4; ++r) {
        float s = 0.f;
#pragma unroll
        for (int nj = 0; nj < 8; ++nj) s += h[nj][r];
        s += __shfl_xor(s, 1); s += __shfl_xor(s, 2);
        s += __shfl_xor(s, 4); s += __shfl_xor(s, 8);
        mu[r] = s * (1.0f / 128.0f);
        float v = 0.f;
#pragma unroll
        for (int nj = 0; nj < 8; ++nj) {
            float d = h[nj][r] - mu[r];
            v = fmaf(d, d, v);
        }
        v += __shfl_xor(v, 1); v += __shfl_xor(v, 2);
        v += __shfl_xor(v, 4); v += __shfl_xor(v, 8);
        rstd[r] = rsqrtf(v * (1.0f / 128.0f) + 1e-3f);
    }

#pragma unroll
    for (int nj = 0; nj < 8; ++nj) {
        int col = c0 + 16 * nj;
        float lg = ln_g[col], lb = ln_b[col];
#pragma unroll
        for (int r = 0; r < 4; ++r) {
            float y = fmaf((h[nj][r] - mu[r]) * rstd[r], lg, lb);
            h1_lds[w][rg * 4 + r][col] = (__bf16)y;
        }
    }

    f32x4 acc2[4];
#pragma unroll
    for (int nj = 0; nj < 4; ++nj) acc2[nj] = (f32x4){0.f, 0.f, 0.f, 0.f};
#pragma unroll
    for (int ks = 0; ks < 4; ++ks) {
        bf16x8 af = *(const bf16x8*)&h1_lds[w][c0][ks * 32 + rg * 8];
#pragma unroll
        for (int nj = 0; nj < 4; ++nj) {
            bf16x8 bf = *(const bf16x8*)&smf_lds[((ks * 4 + nj) * 64 + lane) * 8];
            acc2[nj] = __builtin_amdgcn_mfma_f32_16x16x32_bf16(af, bf, acc2[nj], 0, 0, 0);
        }
    }

    float lgt[4][4];
#pragma unroll
    for (int nj = 0; nj < 4; ++nj) {
        float sb = sm_b[c0 + 16 * nj];
#pragma unroll
        for (int r = 0; r < 4; ++r) lgt[nj][r] = acc2[nj][r] + sb;
    }
#pragma unroll
    for (int r = 0; r < 4; ++r) {
        float mx = fmaxf(fmaxf(lgt[0][r], lgt[1][r]), fmaxf(lgt[2][r], lgt[3][r]));
        mx = fmaxf(mx, __shfl_xor(mx, 1)); mx = fmaxf(mx, __shfl_xor(mx, 2));
        mx = fmaxf(mx, __shfl_xor(mx, 4)); mx = fmaxf(mx, __shfl_xor(mx, 8));
        float ex[4], se = 0.f;
#pragma unroll
        for (int nj = 0; nj < 4; ++nj) {
            ex[nj] = __expf(lgt[nj][r] - mx);
            se += ex[nj];
        }
        se += __shfl_xor(se, 1); se += __shfl_xor(se, 2);
        se += __shfl_xor(se, 4); se += __shfl_xor(se, 8);
        float inv = 1.0f / se;
        int tok = tokb + rg * 4 + r;
#pragma unroll
        for (int nj = 0; nj < 4; ++nj) {
            int f = c0 + 16 * nj;
            float wgt = ex[nj] * inv;
            float xv = x[(size_t)tok * F_DIM + f];
            out[(size_t)tok * F_DIM + f] = xv * wgt;
            out[(size_t)TOK * F_DIM + (size_t)tok * F_DIM + f] = wgt;
        }
    }
}

// ---------------------------------------------------------------------------
extern "C" void kernel_launch(void* const* d_in, const int* in_sizes, int n_in,
                              void* d_out, int out_size, void* d_ws, size_t ws_size,
                              hipStream_t stream)
{
    const float* x      = (const float*)d_in[0];
    const float* fw     = (const float*)d_in[1];
    const float* fb     = (const float*)d_in[2];
    const float* elu_w  = (const float*)d_in[3];
    const float* elu_b  = (const float*)d_in[4];
    const float* lin_w  = (const float*)d_in[5];
    const float* lin_b  = (const float*)d_in[6];
    const float* gate_w = (const float*)d_in[7];
    const float* gate_b = (const float*)d_in[8];
    const float* proj_w = (const float*)d_in[9];
    const float* ln_g   = (const float*)d_in[10];
    const float* ln_b   = (const float*)d_in[11];
    const float* sm_w   = (const float*)d_in[12];
    const float* sm_b   = (const float*)d_in[13];

    // ws: Cw 1.57MB | Hp 25.17MB | linf 32KB | smf 16KB | c_ws 1MB
    char* wsb = (char*)d_ws;
    _Float16* Cw   = (_Float16*)wsb;
    __bf16*   Hp   = (__bf16*)(wsb + (size_t)KCH * N3 * 2);
    __bf16*   linf = (__bf16*)(wsb + (size_t)KCH * N3 * 2
                                   + (size_t)KSPL * TOK * N3 * 2);
    __bf16*   smf  = linf + U_DIM * U_DIM;
    float*    c_ws = (float*)((char*)smf + U_DIM * F_DIM * 2);

    vsn_prep20<<<268, 256, 0, stream>>>(fw, fb, lin_w, sm_w, c_ws, linf, smf);
    vsn_cbuild20<<<dim3(64, 3), 256, 0, stream>>>(c_ws, elu_w, gate_w, proj_w, Cw);
    vsn_gemm20<<<dim3(KSPL, TOK / BM), 256, 0, stream>>>(x, Cw, Hp);
    vsn_epi20<<<TOK / 32, 128, 0, stream>>>(x, Hp, linf, smf, elu_b, lin_b,
                                            gate_b, ln_g, ln_b, sm_b,
                                            (float*)d_out);
}